// Round 14
// baseline (402.693 us; speedup 1.0000x reference)
//
#include <hip/hip_runtime.h>
#include <math.h>

#define BB   4
#define TT   1024
#define CC   768
#define HH   12
#define SS   64
#define FFD  3072
#define HIDD 2048
#define NTOK (BB*TT)          // 4096
#define EPSR 1e-6f

typedef __attribute__((ext_vector_type(8))) short bf16x8;
typedef __attribute__((ext_vector_type(4))) float f32x4;

__device__ __forceinline__ unsigned short f2bf(float f) {
    unsigned u = __float_as_uint(f);
    return (unsigned short)((u + 0x7FFFu + ((u >> 16) & 1u)) >> 16);
}
__device__ __forceinline__ float bfl(unsigned u) { return __uint_as_float(u << 16); }
__device__ __forceinline__ float bfh(unsigned u) { return __uint_as_float(u & 0xFFFF0000u); }
__device__ __forceinline__ unsigned pk2(float a, float b) {
    return (unsigned)f2bf(a) | ((unsigned)f2bf(b) << 16);
}

__device__ __forceinline__ void gload_lds16(const unsigned short* g, unsigned short* l) {
    __builtin_amdgcn_global_load_lds(
        (const __attribute__((address_space(1))) unsigned int*)g,
        (__attribute__((address_space(3))) unsigned int*)l, 16, 0, 0);
}

// ---------------- h_bf16 = bf16(x * rms_scale * gamma[c]) ------------------
__global__ void k_scale_gamma_b(const float* __restrict__ x, const float* __restrict__ g,
                                const float* __restrict__ part, unsigned short* __restrict__ h,
                                int n8, float invn, int npart) {
    __shared__ float sm[256];
    float s = 0.f;
    for (int i = threadIdx.x; i < npart; i += 256) s += part[i];
    sm[threadIdx.x] = s;
    __syncthreads();
    for (int off = 128; off > 0; off >>= 1) {
        if (threadIdx.x < off) sm[threadIdx.x] += sm[threadIdx.x + off];
        __syncthreads();
    }
    float sc = 1.0f / sqrtf(EPSR + sm[0] * invn);
    int i = blockIdx.x * blockDim.x + threadIdx.x;
    if (i >= n8) return;
    float4 v0 = ((const float4*)x)[2*i];
    float4 v1 = ((const float4*)x)[2*i+1];
    int c = (i * 8) % CC;
    float4 g0 = *(const float4*)(g + c);
    float4 g1v = *(const float4*)(g + c + 4);
    uint4 r;
    r.x = pk2(v0.x*sc*g0.x,  v0.y*sc*g0.y);
    r.y = pk2(v0.z*sc*g0.z,  v0.w*sc*g0.w);
    r.z = pk2(v1.x*sc*g1v.x, v1.y*sc*g1v.y);
    r.w = pk2(v1.z*sc*g1v.z, v1.w*sc*g1v.w);
    ((uint4*)h)[i] = r;
}

// ---------------- fused weight prep + rms1 sumsq ---------------------------
#define TQKV 1728
#define TWO  576
#define TW1  2304
#define TWW  6144
#define TWD  6144
#define TW2  2304
#define J0 (TQKV)
#define J1 (J0 + TWO)
#define J2 (J1 + TW1)
#define J3 (J2 + TWW)
#define J4 (J3 + TWW)
#define J5 (J4 + TWD)
#define J6 (J5 + TW2)
#define J7 (J6 + 16)
#define J8 (J7 + 128)
#define JSUM 1024
#define J9 (J8 + JSUM)

__device__ __forceinline__ void wT_tile(float (*tl)[33], const float* __restrict__ W,
                                        unsigned short* __restrict__ Wt,
                                        int K, int N, int t, int tx, int ty) {
    int nk = K >> 5;
    int k0 = (t % nk) * 32, n0 = (t / nk) * 32;
#pragma unroll
    for (int i = 0; i < 4; ++i)
        tl[ty + i*8][tx] = W[(size_t)(k0 + ty + i*8) * N + n0 + tx];
    __syncthreads();
#pragma unroll
    for (int i = 0; i < 4; ++i)
        Wt[(size_t)(n0 + ty + i*8) * K + k0 + tx] = f2bf(tl[tx][ty + i*8]);
}

// 16-block interleave: logical col j -> packed row (j&~15)*2 + ofs*16 + (j&15)
__device__ __forceinline__ void wT_tile_il(float (*tl)[33], const float* __restrict__ W,
                                           unsigned short* __restrict__ Wt,
                                           int K, int N, int t, int tx, int ty, int ofs) {
    int nk = K >> 5;
    int k0 = (t % nk) * 32, n0 = (t / nk) * 32;
#pragma unroll
    for (int i = 0; i < 4; ++i)
        tl[ty + i*8][tx] = W[(size_t)(k0 + ty + i*8) * N + n0 + tx];
    __syncthreads();
#pragma unroll
    for (int i = 0; i < 4; ++i) {
        int j = n0 + ty + i*8;
        int pr = ((j & ~15) << 1) + ofs*16 + (j & 15);
        Wt[(size_t)pr * K + k0 + tx] = f2bf(tl[tx][ty + i*8]);
    }
}

__global__ void k_prep(const float* __restrict__ Wq, const float* __restrict__ Wk,
                       const float* __restrict__ Wv, const float* __restrict__ Wo,
                       const float* __restrict__ W1, const float* __restrict__ Ww,
                       const float* __restrict__ Wg, const float* __restrict__ Wd,
                       const float* __restrict__ W2, const float* __restrict__ bw,
                       const float* __restrict__ bg, const float* __restrict__ x,
                       unsigned short* __restrict__ wqkvT, unsigned short* __restrict__ WoT,
                       unsigned short* __restrict__ W1T, unsigned short* __restrict__ WcatT,
                       unsigned short* __restrict__ WdT, unsigned short* __restrict__ W2T,
                       float* __restrict__ bcat, float* __restrict__ tab,
                       float* __restrict__ part) {
    __shared__ float tl[32][33];
    const int bid = blockIdx.x;
    const int tx = threadIdx.x & 31, ty = threadIdx.x >> 5;
    if (bid < J0) {
        int t = bid;
        int c0 = (t % 24) * 32;
        int s0 = ((t / 24) & 1) * 32;
        int z = t / 48, sel = z / HH, h = z % HH;
        const float* W = (sel == 0 ? Wq : (sel == 1 ? Wk : Wv)) + (size_t)h * CC * SS;
#pragma unroll
        for (int i = 0; i < 4; ++i)
            tl[ty + i*8][tx] = W[(size_t)(c0 + ty + i*8) * SS + s0 + tx];
        __syncthreads();
#pragma unroll
        for (int i = 0; i < 4; ++i)
            wqkvT[(size_t)(sel*CC + h*SS + s0 + ty + i*8) * CC + c0 + tx] = f2bf(tl[tx][ty + i*8]);
    } else if (bid < J1) {
        wT_tile(tl, Wo, WoT, CC, CC, bid - J0, tx, ty);
    } else if (bid < J2) {
        wT_tile(tl, W1, W1T, CC, FFD, bid - J1, tx, ty);
    } else if (bid < J3) {
        wT_tile_il(tl, Ww, WcatT, FFD, HIDD, bid - J2, tx, ty, 0);
    } else if (bid < J4) {
        wT_tile_il(tl, Wg, WcatT, FFD, HIDD, bid - J3, tx, ty, 1);
    } else if (bid < J5) {
        wT_tile(tl, Wd, WdT, HIDD, FFD, bid - J4, tx, ty);
    } else if (bid < J6) {
        wT_tile(tl, W2, W2T, FFD, CC, bid - J5, tx, ty);
    } else if (bid < J7) {
        int ip = (bid - J6) * 256 + threadIdx.x;   // packed index in [0,4096)
        int lg = ((ip >> 5) << 4) + (ip & 15);     // logical col
        bcat[ip] = ((ip >> 4) & 1) ? bg[lg] : bw[lg];
    } else if (bid < J8) {
        int i = (bid - J7) * 256 + threadIdx.x;   // T*32
        int t = i >> 5, j = i & 31;
        float th = expf(-(float)j * 0.5756462732485115f);  // 10000^(-j/16)
        float ang = (float)t * th;
        tab[2*i]   = cosf(ang);
        tab[2*i+1] = sinf(ang);
    } else {
        float* sm = &tl[0][0];
        const int pb = bid - J8;
        const int n4 = NTOK * CC / 4;
        float s = 0.f;
        int stride = JSUM * 256;
        for (int i = pb * 256 + threadIdx.x; i < n4; i += stride) {
            float4 v = ((const float4*)x)[i];
            s += v.x*v.x + v.y*v.y + v.z*v.z + v.w*v.w;
        }
        sm[threadIdx.x] = s;
        __syncthreads();
        for (int off = 128; off > 0; off >>= 1) {
            if (threadIdx.x < off) sm[threadIdx.x] += sm[threadIdx.x + off];
            __syncthreads();
        }
        if (threadIdx.x == 0) part[pb] = sm[0];
    }
}

// ---------------- fused rope-apply (q,k) + V transpose --------------------
__global__ void k_rope_vt(unsigned short* __restrict__ qkv, const float* __restrict__ tab,
                          unsigned short* __restrict__ vtg) {
    const int bid = blockIdx.x;
    if (bid < 6144) {
        int i = bid * 256 + threadIdx.x;          // NTOK*H*32
        int j  = i & 31;
        int h  = (i >> 5) % HH;
        int bt = i / (32 * HH);
        int t  = bt & (TT - 1);
        float cs = tab[(t*32 + j)*2];
        float sn = tab[(t*32 + j)*2 + 1];
        size_t base = (size_t)bt * (3*CC) + h * SS + 2*j;
        unsigned q = *(unsigned*)(qkv + base);
        float qe = bfl(q), qo = bfh(q);
        *(unsigned*)(qkv + base) = pk2(qe*cs - qo*sn, qo*cs + qe*sn);
        unsigned k = *(unsigned*)(qkv + base + CC);
        float ke = bfl(k), ko = bfh(k);
        *(unsigned*)(qkv + base + CC) = pk2(ke*cs - ko*sn, ko*cs + ke*sn);
    } else {
        int b2 = bid - 6144;                      // 384 blocks: bh 0..47, ty 0..7
        int bh = b2 >> 3, ty = b2 & 7;
        int b = bh / HH, h = bh % HH;
        int d = threadIdx.x & 63, tq = threadIdx.x >> 6;
        int t0 = ty * 128 + tq * 32;
        const unsigned short* src = qkv + (size_t)(b*TT + t0)*(3*CC) + 2*CC + h*SS + d;
        unsigned v[16];
#pragma unroll
        for (int e = 0; e < 16; ++e) {
            unsigned lo = src[(size_t)(2*e)*(3*CC)];
            unsigned hi = src[(size_t)(2*e+1)*(3*CC)];
            v[e] = (lo & 0xFFFFu) | (hi << 16);
        }
        uint4* dst = (uint4*)(vtg + ((size_t)bh*64 + d)*TT + t0);
#pragma unroll
        for (int q = 0; q < 4; ++q)
            dst[q] = make_uint4(v[q*4], v[q*4+1], v[q*4+2], v[q*4+3]);
    }
}

// ---------------- 128x128 bf16 MFMA GEMM (2-phase) — small-N cases --------
template<bool BIAS, bool RES, bool OUTB, bool SSQ>
__global__ __launch_bounds__(256) void k_gemm_bf16(
    const unsigned short* __restrict__ A, const unsigned short* __restrict__ Bt,
    const float* __restrict__ bias, const float* __restrict__ res,
    void* __restrict__ Cv, int M, int N, int K, float* __restrict__ ssq_part)
{
    __shared__ unsigned short As[2][128*32];
    __shared__ unsigned short Bs[2][128*32];
    __shared__ float smr[256];
    const int tid  = threadIdx.x;
    const int w    = tid >> 6, lane = tid & 63;
    const int wr   = w >> 1,  wc   = w & 1;
    const int row0 = blockIdx.y * 128, col0 = blockIdx.x * 128;

    f32x4 acc[4][4];
#pragma unroll
    for (int m = 0; m < 4; ++m)
#pragma unroll
        for (int n = 0; n < 4; ++n) acc[m][n] = (f32x4){0.f, 0.f, 0.f, 0.f};

    const int lr4 = lane >> 2;
    const int scb = lane & 3;

    auto stage = [&](int t, int buf) {
#pragma unroll
        for (int i = 0; i < 2; ++i) {
            int lr = w * 32 + i * 16 + lr4;
            int cbs = scb ^ ((lr >> 1) & 3);
            const unsigned short* ga = A + (size_t)(row0 + lr) * K + t * 32 + cbs * 8;
            gload_lds16(ga, &As[buf][(w * 32 + i * 16) * 32]);
            const unsigned short* gb = Bt + (size_t)(col0 + lr) * K + t * 32 + cbs * 8;
            gload_lds16(gb, &Bs[buf][(w * 32 + i * 16) * 32]);
        }
    };

    const int nt = K / 32;
    stage(0, 0);
    int cur = 0;
    const int fr = lane & 15, fq = lane >> 4;
    for (int t = 0; t < nt; ++t) {
        __syncthreads();
        if (t + 1 < nt) stage(t + 1, cur ^ 1);
        bf16x8 af[4], bf[4];
#pragma unroll
        for (int m = 0; m < 4; ++m) {
            int ra = wr * 64 + m * 16 + fr;
            af[m] = *(const bf16x8*)&As[cur][ra * 32 + (fq ^ ((ra >> 1) & 3)) * 8];
            int rb = wc * 64 + m * 16 + fr;
            bf[m] = *(const bf16x8*)&Bs[cur][rb * 32 + (fq ^ ((rb >> 1) & 3)) * 8];
        }
#pragma unroll
        for (int m = 0; m < 4; ++m)
#pragma unroll
            for (int n = 0; n < 4; ++n)
                acc[m][n] = __builtin_amdgcn_mfma_f32_16x16x32_bf16(af[m], bf[n], acc[m][n], 0, 0, 0);
        cur ^= 1;
    }

    float ssq = 0.f;
#pragma unroll
    for (int m = 0; m < 4; ++m) {
#pragma unroll
        for (int n = 0; n < 4; ++n) {
            int col = col0 + wc * 64 + n * 16 + fr;
            float bv = BIAS ? bias[col] : 0.f;
#pragma unroll
            for (int j = 0; j < 4; ++j) {
                int row = row0 + wr * 64 + m * 16 + fq * 4 + j;
                size_t off = (size_t)row * N + col;
                float v = acc[m][n][j] + bv;
                if (RES) v += res[off];
                if (OUTB) ((unsigned short*)Cv)[off] = f2bf(v);
                else      ((float*)Cv)[off] = v;
                if (SSQ) ssq += v * v;
            }
        }
    }
    if (SSQ) {
        smr[tid] = ssq;
        __syncthreads();
        for (int off = 128; off > 0; off >>= 1) {
            if (tid < off) smr[tid] += smr[tid + off];
            __syncthreads();
        }
        if (tid == 0) ssq_part[blockIdx.y * gridDim.x + blockIdx.x] = smr[0];
    }
}

// ---------------- 128x256 bf16 MFMA GEMM — ring-3, 2 blocks/CU -------------
// 8 waves (2M x 4N), per-wave 64x64. LDS ring-3 x (A 8KB + B 16KB) = 72KB ->
// 2 blocks/CU (cross-block overlap hides barrier/drain stalls). Counted vmcnt:
// 3 loads/thread/step; stage(s+2); gate vmcnt(3) = slot s+1 landed, s+2 in
// flight. T2 source-side swizzle; T5 setprio. Lane-local SWIGLU epilogue.
#define GSTEP(SL, STG, SNUM, DOSTAGE, GATE)                                       \
    {                                                                             \
        const unsigned short* pa_ = &ringA[SL][0];                                \
        const unsigned short* pb_ = &ringB[SL][0];                                \
        bf16x8 af[4], bv[4];                                                      \
        _Pragma("unroll")                                                         \
        for (int m = 0; m < 4; ++m)                                               \
            af[m] = *(const bf16x8*)&pa_[offA[m]];                                \
        _Pragma("unroll")                                                         \
        for (int n = 0; n < 4; ++n)                                               \
            bv[n] = *(const bf16x8*)&pb_[offB[n]];                                \
        if (DOSTAGE) { stageA(SNUM, STG); stageB(SNUM, STG); }                    \
        asm volatile("s_waitcnt lgkmcnt(0)" ::: "memory");                        \
        __builtin_amdgcn_sched_barrier(0);                                        \
        __builtin_amdgcn_s_setprio(1);                                            \
        _Pragma("unroll")                                                         \
        for (int m = 0; m < 4; ++m)                                               \
            _Pragma("unroll")                                                     \
            for (int n = 0; n < 4; ++n)                                           \
                acc[m][n] = __builtin_amdgcn_mfma_f32_16x16x32_bf16(              \
                    af[m], bv[n], acc[m][n], 0, 0, 0);                            \
        __builtin_amdgcn_s_setprio(0);                                            \
        asm volatile("s_waitcnt " GATE ::: "memory");                             \
        __builtin_amdgcn_sched_barrier(0);                                        \
        __builtin_amdgcn_s_barrier();                                             \
    }

template<bool BIAS, bool SWIGLU>
__global__ __launch_bounds__(512, 4) void k_gemm256(
    const unsigned short* __restrict__ A, const unsigned short* __restrict__ Bt,
    const float* __restrict__ bias, unsigned short* __restrict__ C,
    int M, int N, int K)
{
    __shared__ __align__(16) unsigned short ringA[3][128*32];
    __shared__ __align__(16) unsigned short ringB[3][256*32];
    const int tid = threadIdx.x;
    const int w = tid >> 6, lane = tid & 63;
    const int wm = w >> 2, wn = w & 3;
    const int fr = lane & 15, fq = lane >> 4;

    // XCD-bijective swizzle (all grids have nwg % 8 == 0)
    const int nwg = gridDim.x * gridDim.y;
    const int bid = blockIdx.y * gridDim.x + blockIdx.x;
    const int cpx = nwg >> 3;
    const int sbid = (bid & 7) * cpx + (bid >> 3);
    const int row0 = (sbid / gridDim.x) * 128;
    const int col0 = (sbid % gridDim.x) * 256;

    f32x4 acc[4][4];
#pragma unroll
    for (int m = 0; m < 4; ++m)
#pragma unroll
        for (int n = 0; n < 4; ++n) acc[m][n] = (f32x4){0.f, 0.f, 0.f, 0.f};

    // hoisted stage source pointers (only kb = t*32 varies)
    const int c0 = tid, c1 = 512 + tid;
    const int r0 = c0 >> 2, p0 = ((c0 & 3) ^ ((r0 >> 1) & 3)) * 8;
    const int r1 = c1 >> 2, p1 = ((c1 & 3) ^ ((r1 >> 1) & 3)) * 8;
    const unsigned short* aS0 = A  + (size_t)(row0 + r0) * K + p0;   // rows 0..127
    const unsigned short* bS0 = Bt + (size_t)(col0 + r0) * K + p0;   // rows 0..127
    const unsigned short* bS1 = Bt + (size_t)(col0 + r1) * K + p1;   // rows 128..255
    const int dL = w * 512;            // per-wave LDS dst offset (elements)
    auto stageA = [&](int t, int sl) {
        gload_lds16(aS0 + t * 32, &ringA[sl][dL]);
    };
    auto stageB = [&](int t, int sl) {
        const int kb = t * 32;
        gload_lds16(bS0 + kb, &ringB[sl][dL]);
        gload_lds16(bS1 + kb, &ringB[sl][4096 + dL]);
    };

    // hoisted frag read offsets
    int offA[4], offB[4];
#pragma unroll
    for (int m = 0; m < 4; ++m) {
        int ra = wm*64 + m*16 + fr;
        offA[m] = ra*32 + (fq ^ ((ra >> 1) & 3))*8;
    }
#pragma unroll
    for (int n = 0; n < 4; ++n) {
        int rb = wn*64 + n*16 + fr;
        offB[n] = rb*32 + (fq ^ ((rb >> 1) & 3))*8;
    }

    const int S = K >> 5;     // k32 steps (>= 24)
    stageA(0, 0); stageB(0, 0); stageA(1, 1); stageB(1, 1);
    asm volatile("s_waitcnt vmcnt(3)" ::: "memory");   // slot 0 landed
    __builtin_amdgcn_s_barrier();

    int sl = 0, stg = 2;
    for (int s = 0; s < S - 2; ++s) {
        GSTEP(sl, stg, s + 2, true, "vmcnt(3)");
        sl  = (sl  == 2) ? 0 : sl  + 1;
        stg = (stg == 2) ? 0 : stg + 1;
    }
    GSTEP(sl, 0, 0, false, "vmcnt(0)");
    sl = (sl == 2) ? 0 : sl + 1;
    GSTEP(sl, 0, 0, false, "vmcnt(0)");

    // epilogue: row = row0 + wm*64 + m*16 + fq*4 + j, col = col0 + wn*64 + n*16 + fr
    if (SWIGLU) {
#pragma unroll
        for (int m = 0; m < 4; ++m) {
#pragma unroll
            for (int n = 0; n < 4; n += 2) {
                int colw = col0 + wn*64 + n*16 + fr;         // packed wx col
                float bw_ = BIAS ? bias[colw] : 0.f;
                float bg_ = BIAS ? bias[colw + 16] : 0.f;
                int colo = ((colw >> 5) << 4) + (colw & 15); // logical out col
#pragma unroll
                for (int j = 0; j < 4; ++j) {
                    int row = row0 + wm*64 + m*16 + fq*4 + j;
                    float wx = acc[m][n][j] + bw_;
                    float vx = acc[m][n+1][j] + bg_;
                    float sw = wx * vx / (1.f + __expf(-vx));
                    C[(size_t)row * (N >> 1) + colo] = f2bf(sw);
                }
            }
        }
    } else {
#pragma unroll
        for (int m = 0; m < 4; ++m) {
#pragma unroll
            for (int n = 0; n < 4; ++n) {
                int col = col0 + wn*64 + n*16 + fr;
                float bvb = BIAS ? bias[col] : 0.f;
#pragma unroll
                for (int j = 0; j < 4; ++j) {
                    int row = row0 + wm*64 + m*16 + fq*4 + j;
                    C[(size_t)row * N + col] = f2bf(acc[m][n][j] + bvb);
                }
            }
        }
    }
}

// ---------------- MFMA flash attention (causal), bf16 --------------------
__global__ __launch_bounds__(256) void k_attn_mfma(
    const unsigned short* __restrict__ qkv, const unsigned short* __restrict__ vtg,
    unsigned short* __restrict__ attn)
{
    __shared__ __align__(16) unsigned short Ks[2][64*64];
    __shared__ __align__(16) unsigned short Vs[2][64*64];
    __shared__ __align__(16) unsigned short Ps[4][16*72];
    const int tid = threadIdx.x;
    const int w = tid >> 6, lane = tid & 63;
    const int fr = lane & 15, fq = lane >> 4;
    const int bh = blockIdx.x, b = bh / HH, h = bh % HH;
    const int qb = blockIdx.y * 64;
    const int nkt = qb / 64 + 1;
    const float scale = 0.03608439182435161f;  // 768^-0.5

    bf16x8 qf[2];
    {
        const unsigned short* qp = qkv + (size_t)(b*TT + qb + w*16 + fr)*(3*CC) + h*SS + fq*8;
        qf[0] = *(const bf16x8*)qp;
        qf[1] = *(const bf16x8*)(qp + 32);
    }

    auto stage = [&](int kt, int buf) {
        const unsigned short* kbase = qkv + (size_t)(b*TT + kt*64)*(3*CC) + CC + h*SS;
        const unsigned short* vbase = vtg + ((size_t)bh*64)*TT + kt*64;
#pragma unroll
        for (int p = 0; p < 2; ++p) {
            int s = p*256 + tid;
            int row = s >> 3;
            int blk = (s & 7) ^ (row & 7);
            gload_lds16(kbase + (size_t)row*(3*CC) + blk*8, &Ks[buf][(p*256 + w*64)*8]);
            gload_lds16(vbase + (size_t)row*TT + blk*8,     &Vs[buf][(p*256 + w*64)*8]);
        }
    };

    float m[4] = {-INFINITY, -INFINITY, -INFINITY, -INFINITY};
    float l[4] = {0.f, 0.f, 0.f, 0.f};
    f32x4 oacc[4];
#pragma unroll
    for (int n = 0; n < 4; ++n) oacc[n] = (f32x4){0.f, 0.f, 0.f, 0.f};

    stage(0, 0);
    int cur = 0;
    for (int kt = 0; kt < nkt; ++kt) {
        __syncthreads();
        if (kt + 1 < nkt) stage(kt + 1, cur ^ 1);

        f32x4 sacc[4];
#pragma unroll
        for (int n = 0; n < 4; ++n) sacc[n] = (f32x4){0.f, 0.f, 0.f, 0.f};
#pragma unroll
        for (int ks = 0; ks < 2; ++ks) {
#pragma unroll
            for (int n = 0; n < 4; ++n) {
                int row = n*16 + fr;
                bf16x8 kf = *(const bf16x8*)&Ks[cur][row*64 + ((ks*4 + fq) ^ (row & 7))*8];
                sacc[n] = __builtin_amdgcn_mfma_f32_16x16x32_bf16(qf[ks], kf, sacc[n], 0, 0, 0);
            }
        }

        float sv[4][4];
        const bool lastt = (kt == nkt - 1);
        const int qloc = w*16 + fq*4;
#pragma unroll
        for (int n = 0; n < 4; ++n) {
            int kloc = n*16 + fr;
#pragma unroll
            for (int j = 0; j < 4; ++j) {
                float vv = sacc[n][j] * scale;
                if (lastt && kloc > qloc + j) vv = -INFINITY;
                sv[j][n] = vv;
            }
        }
        float mx[4], ls[4];
#pragma unroll
        for (int j = 0; j < 4; ++j)
            mx[j] = fmaxf(fmaxf(sv[j][0], sv[j][1]), fmaxf(sv[j][2], sv[j][3]));
#pragma unroll
        for (int d = 1; d < 16; d <<= 1)
#pragma unroll
            for (int j = 0; j < 4; ++j) mx[j] = fmaxf(mx[j], __shfl_xor(mx[j], d));
        float corr[4];
#pragma unroll
        for (int j = 0; j < 4; ++j) {
            float nm = fmaxf(m[j], mx[j]);
            corr[j] = __expf(m[j] - nm);
            m[j] = nm;
        }
#pragma unroll
        for (int j = 0; j < 4; ++j) {
            float s0 = 0.f;
#pragma unroll
            for (int n = 0; n < 4; ++n) {
                float p = __expf(sv[j][n] - m[j]);
                sv[j][n] = p;
                s0 += p;
            }
            ls[j] = s0;
        }
#pragma unroll
        for (int d = 1; d < 16; d <<= 1)
#pragma unroll
            for (int j = 0; j < 4; ++j) ls[j] += __shfl_xor(ls[j], d);
#pragma unroll
        for (int j = 0; j < 4; ++j) l[j] = l[j]*corr[j] + ls[j];
#pragma unroll
        for (int n = 0; n < 4; ++n)
#pragma unroll
            for (int j = 0; j < 4; ++j) oacc[n][j] *= corr[j];

#pragma unroll
        for (int j = 0; j < 4; ++j)
#pragma unroll
            for (int n = 0; n < 4; ++n)
                Ps[w][(fq*4 + j)*72 + n*16 + fr] = f2bf(sv[j][n]);

#pragma unroll
        for (int ks = 0; ks < 2; ++ks) {
            bf16x8 pf = *(const bf16x8*)&Ps[w][fr*72 + ks*32 + fq*8];
#pragma unroll
            for (int n = 0; n < 4; ++n) {
                int row = n*16 + fr;
                bf16x8 vf = *(const bf16x8*)&Vs[cur][row*64 + ((ks*4 + fq) ^ (row & 7))*8];
                oacc[n] = __builtin_amdgcn_mfma_f32_16x16x32_bf16(pf, vf, oacc[n], 0, 0, 0);
            }
        }
        cur ^= 1;
    }

    float inv[4];
#pragma unroll
    for (int j = 0; j < 4; ++j) inv[j] = 1.0f / l[j];
#pragma unroll
    for (int n = 0; n < 4; ++n)
#pragma unroll
        for (int j = 0; j < 4; ++j) {
            size_t off = (size_t)(b*TT + qb + w*16 + fq*4 + j)*CC + h*SS + n*16 + fr;
            attn[off] = f2bf(oacc[n][j] * inv[j]);
        }
}

// ---------------- launch ---------------------------------------------------
extern "C" void kernel_launch(void* const* d_in, const int* in_sizes, int n_in,
                              void* d_out, int out_size, void* d_ws, size_t ws_size,
                              hipStream_t stream)
{
    const float* x  = (const float*)d_in[0];
    const float* Wq = (const float*)d_in[1];
    const float* Wk = (const float*)d_in[2];
    const float* Wv = (const float*)d_in[3];
    const float* Wo = (const float*)d_in[4];
    const float* g1 = (const float*)d_in[5];
    const float* g2 = (const float*)d_in[6];
    const float* W1 = (const float*)d_in[7];
    const float* b1 = (const float*)d_in[8];
    const float* Ww = (const float*)d_in[9];
    const float* bw = (const float*)d_in[10];
    const float* Wg = (const float*)d_in[11];
    const float* bg = (const float*)d_in[12];
    const float* Wd = (const float*)d_in[13];
    const float* bd = (const float*)d_in[14];
    const float* W2 = (const float*)d_in[15];
    const float* b2 = (const float*)d_in[16];
    float* out = (float*)d_out;

    char* p = (char*)d_ws;
    auto alloc = [&](size_t bytes) { char* r = p; p += (bytes + 255) & ~(size_t)255; return r; };

    float*          part   = (float*)alloc(4096);
    float*          tab    = (float*)alloc((size_t)TT*32*2*4);
    float*          bcat   = (float*)alloc((size_t)2*HIDD*4);
    unsigned short* hb     = (unsigned short*)alloc((size_t)NTOK*CC*2);
    unsigned short* wqkvT  = (unsigned short*)alloc((size_t)3*CC*CC*2);
    unsigned short* qkvb   = (unsigned short*)alloc((size_t)NTOK*3*CC*2);
    unsigned short* vtg    = (unsigned short*)alloc((size_t)BB*HH*SS*TT*2);
    unsigned short* attnb  = (unsigned short*)alloc((size_t)NTOK*CC*2);
    unsigned short* WoT    = (unsigned short*)alloc((size_t)CC*CC*2);
    unsigned short* W1T    = (unsigned short*)alloc((size_t)FFD*CC*2);
    unsigned short* ub     = (unsigned short*)alloc((size_t)NTOK*FFD*2);
    unsigned short* WcatT  = (unsigned short*)alloc((size_t)2*HIDD*FFD*2);
    unsigned short* swb    = (unsigned short*)alloc((size_t)NTOK*HIDD*2);
    unsigned short* WdT    = (unsigned short*)alloc((size_t)FFD*HIDD*2);
    unsigned short* W2T    = (unsigned short*)alloc((size_t)CC*FFD*2);

    const int n = NTOK * CC;

    // fused weight prep + rms1 sumsq
    k_prep<<<J9, 256, 0, stream>>>(Wq, Wk, Wv, Wo, W1, Ww, Wg, Wd, W2, bw, bg, x,
                                   wqkvT, WoT, W1T, WcatT, WdT, W2T, bcat, tab, part);

    // rms1 -> h (bf16)
    k_scale_gamma_b<<<(n/8)/256, 256, 0, stream>>>(x, g1, part, hb, n/8,
                                                   1.0f/(float)n, JSUM);

    // qkv = h @ WqkvT^T  (128x256 ring3)
    k_gemm256<false,false><<<dim3(3*CC/256, NTOK/128), 512, 0, stream>>>(
        hb, wqkvT, nullptr, qkvb, NTOK, 3*CC, CC);
    // rope(q,k) + V transpose (fused)
    k_rope_vt<<<6144 + 384, 256, 0, stream>>>(qkvb, tab, vtg);

    // attention (MFMA)
    k_attn_mfma<<<dim3(BB*HH, TT/64), 256, 0, stream>>>(qkvb, vtg, attnb);

    // out1 = attn @ Wo + x  (128^2, fp32 out) + fused rms2 sumsq partials
    k_gemm_bf16<false,true,false,true><<<dim3(CC/128, NTOK/128), 256, 0, stream>>>(
        attnb, WoT, nullptr, x, out, NTOK, CC, CC, part);

    // rms2 -> h2 (reduces 192 partials from Wo epilogue)
    k_scale_gamma_b<<<(n/8)/256, 256, 0, stream>>>(out, g2, part, hb, n/8,
                                                   1.0f/(float)n, (CC/128)*(NTOK/128));

    // u = h2 @ W1 + b1  (ring3)
    k_gemm256<true,false><<<dim3(FFD/256, NTOK/128), 512, 0, stream>>>(
        hb, W1T, b1, ub, NTOK, FFD, CC);
    // swb = swiglu(u @ WcatT + bcat)  (lane-local fused epilogue, ring3)
    k_gemm256<true,true><<<dim3(2*HIDD/256, NTOK/128), 512, 0, stream>>>(
        ub, WcatT, bcat, swb, NTOK, 2*HIDD, FFD);
    // ffmid = sw @ Wd + bd  (ring3)
    k_gemm256<true,false><<<dim3(FFD/256, NTOK/128), 512, 0, stream>>>(
        swb, WdT, bd, ub, NTOK, FFD, HIDD);
    // out = out1 + ffmid @ W2 + b2  (128^2, fp32 out + residual)
    k_gemm_bf16<true,true,false,false><<<dim3(CC/128, NTOK/128), 256, 0, stream>>>(
        ub, W2T, b2, out, out, NTOK, CC, FFD, nullptr);
}

// Round 15
// 378.529 us; speedup vs baseline: 1.0638x; 1.0638x over previous
//
#include <hip/hip_runtime.h>
#include <math.h>

#define BB   4
#define TT   1024
#define CC   768
#define HH   12
#define SS   64
#define FFD  3072
#define HIDD 2048
#define NTOK (BB*TT)          // 4096
#define EPSR 1e-6f

typedef __attribute__((ext_vector_type(8))) short bf16x8;
typedef __attribute__((ext_vector_type(4))) float f32x4;

__device__ __forceinline__ unsigned short f2bf(float f) {
    unsigned u = __float_as_uint(f);
    return (unsigned short)((u + 0x7FFFu + ((u >> 16) & 1u)) >> 16);
}
__device__ __forceinline__ float bfl(unsigned u) { return __uint_as_float(u << 16); }
__device__ __forceinline__ float bfh(unsigned u) { return __uint_as_float(u & 0xFFFF0000u); }
__device__ __forceinline__ unsigned pk2(float a, float b) {
    return (unsigned)f2bf(a) | ((unsigned)f2bf(b) << 16);
}

__device__ __forceinline__ void gload_lds16(const unsigned short* g, unsigned short* l) {
    __builtin_amdgcn_global_load_lds(
        (const __attribute__((address_space(1))) unsigned int*)g,
        (__attribute__((address_space(3))) unsigned int*)l, 16, 0, 0);
}

// ---------------- h_bf16 = bf16(x * rms_scale * gamma[c]) ------------------
__global__ void k_scale_gamma_b(const float* __restrict__ x, const float* __restrict__ g,
                                const float* __restrict__ part, unsigned short* __restrict__ h,
                                int n8, float invn, int npart) {
    __shared__ float sm[256];
    float s = 0.f;
    for (int i = threadIdx.x; i < npart; i += 256) s += part[i];
    sm[threadIdx.x] = s;
    __syncthreads();
    for (int off = 128; off > 0; off >>= 1) {
        if (threadIdx.x < off) sm[threadIdx.x] += sm[threadIdx.x + off];
        __syncthreads();
    }
    float sc = 1.0f / sqrtf(EPSR + sm[0] * invn);
    int i = blockIdx.x * blockDim.x + threadIdx.x;
    if (i >= n8) return;
    float4 v0 = ((const float4*)x)[2*i];
    float4 v1 = ((const float4*)x)[2*i+1];
    int c = (i * 8) % CC;
    float4 g0 = *(const float4*)(g + c);
    float4 g1v = *(const float4*)(g + c + 4);
    uint4 r;
    r.x = pk2(v0.x*sc*g0.x,  v0.y*sc*g0.y);
    r.y = pk2(v0.z*sc*g0.z,  v0.w*sc*g0.w);
    r.z = pk2(v1.x*sc*g1v.x, v1.y*sc*g1v.y);
    r.w = pk2(v1.z*sc*g1v.z, v1.w*sc*g1v.w);
    ((uint4*)h)[i] = r;
}

// ---------------- fused weight prep + rms1 sumsq ---------------------------
#define TQKV 1728
#define TWO  576
#define TW1  2304
#define TWW  6144
#define TWD  6144
#define TW2  2304
#define J0 (TQKV)
#define J1 (J0 + TWO)
#define J2 (J1 + TW1)
#define J3 (J2 + TWW)
#define J4 (J3 + TWW)
#define J5 (J4 + TWD)
#define J6 (J5 + TW2)
#define J7 (J6 + 16)
#define J8 (J7 + 128)
#define JSUM 1024
#define J9 (J8 + JSUM)

__device__ __forceinline__ void wT_tile(float (*tl)[33], const float* __restrict__ W,
                                        unsigned short* __restrict__ Wt,
                                        int K, int N, int t, int tx, int ty) {
    int nk = K >> 5;
    int k0 = (t % nk) * 32, n0 = (t / nk) * 32;
#pragma unroll
    for (int i = 0; i < 4; ++i)
        tl[ty + i*8][tx] = W[(size_t)(k0 + ty + i*8) * N + n0 + tx];
    __syncthreads();
#pragma unroll
    for (int i = 0; i < 4; ++i)
        Wt[(size_t)(n0 + ty + i*8) * K + k0 + tx] = f2bf(tl[tx][ty + i*8]);
}

// 16-block interleave: logical col j -> packed row (j&~15)*2 + ofs*16 + (j&15)
__device__ __forceinline__ void wT_tile_il(float (*tl)[33], const float* __restrict__ W,
                                           unsigned short* __restrict__ Wt,
                                           int K, int N, int t, int tx, int ty, int ofs) {
    int nk = K >> 5;
    int k0 = (t % nk) * 32, n0 = (t / nk) * 32;
#pragma unroll
    for (int i = 0; i < 4; ++i)
        tl[ty + i*8][tx] = W[(size_t)(k0 + ty + i*8) * N + n0 + tx];
    __syncthreads();
#pragma unroll
    for (int i = 0; i < 4; ++i) {
        int j = n0 + ty + i*8;
        int pr = ((j & ~15) << 1) + ofs*16 + (j & 15);
        Wt[(size_t)pr * K + k0 + tx] = f2bf(tl[tx][ty + i*8]);
    }
}

__global__ void k_prep(const float* __restrict__ Wq, const float* __restrict__ Wk,
                       const float* __restrict__ Wv, const float* __restrict__ Wo,
                       const float* __restrict__ W1, const float* __restrict__ Ww,
                       const float* __restrict__ Wg, const float* __restrict__ Wd,
                       const float* __restrict__ W2, const float* __restrict__ bw,
                       const float* __restrict__ bg, const float* __restrict__ x,
                       unsigned short* __restrict__ wqkvT, unsigned short* __restrict__ WoT,
                       unsigned short* __restrict__ W1T, unsigned short* __restrict__ WcatT,
                       unsigned short* __restrict__ WdT, unsigned short* __restrict__ W2T,
                       float* __restrict__ bcat, float* __restrict__ tab,
                       float* __restrict__ part) {
    __shared__ float tl[32][33];
    const int bid = blockIdx.x;
    const int tx = threadIdx.x & 31, ty = threadIdx.x >> 5;
    if (bid < J0) {
        int t = bid;
        int c0 = (t % 24) * 32;
        int s0 = ((t / 24) & 1) * 32;
        int z = t / 48, sel = z / HH, h = z % HH;
        const float* W = (sel == 0 ? Wq : (sel == 1 ? Wk : Wv)) + (size_t)h * CC * SS;
#pragma unroll
        for (int i = 0; i < 4; ++i)
            tl[ty + i*8][tx] = W[(size_t)(c0 + ty + i*8) * SS + s0 + tx];
        __syncthreads();
#pragma unroll
        for (int i = 0; i < 4; ++i)
            wqkvT[(size_t)(sel*CC + h*SS + s0 + ty + i*8) * CC + c0 + tx] = f2bf(tl[tx][ty + i*8]);
    } else if (bid < J1) {
        wT_tile(tl, Wo, WoT, CC, CC, bid - J0, tx, ty);
    } else if (bid < J2) {
        wT_tile(tl, W1, W1T, CC, FFD, bid - J1, tx, ty);
    } else if (bid < J3) {
        wT_tile_il(tl, Ww, WcatT, FFD, HIDD, bid - J2, tx, ty, 0);
    } else if (bid < J4) {
        wT_tile_il(tl, Wg, WcatT, FFD, HIDD, bid - J3, tx, ty, 1);
    } else if (bid < J5) {
        wT_tile(tl, Wd, WdT, HIDD, FFD, bid - J4, tx, ty);
    } else if (bid < J6) {
        wT_tile(tl, W2, W2T, FFD, CC, bid - J5, tx, ty);
    } else if (bid < J7) {
        int ip = (bid - J6) * 256 + threadIdx.x;   // packed index in [0,4096)
        int lg = ((ip >> 5) << 4) + (ip & 15);     // logical col
        bcat[ip] = ((ip >> 4) & 1) ? bg[lg] : bw[lg];
    } else if (bid < J8) {
        int i = (bid - J7) * 256 + threadIdx.x;   // T*32
        int t = i >> 5, j = i & 31;
        float th = expf(-(float)j * 0.5756462732485115f);  // 10000^(-j/16)
        float ang = (float)t * th;
        tab[2*i]   = cosf(ang);
        tab[2*i+1] = sinf(ang);
    } else {
        float* sm = &tl[0][0];
        const int pb = bid - J8;
        const int n4 = NTOK * CC / 4;
        float s = 0.f;
        int stride = JSUM * 256;
        for (int i = pb * 256 + threadIdx.x; i < n4; i += stride) {
            float4 v = ((const float4*)x)[i];
            s += v.x*v.x + v.y*v.y + v.z*v.z + v.w*v.w;
        }
        sm[threadIdx.x] = s;
        __syncthreads();
        for (int off = 128; off > 0; off >>= 1) {
            if (threadIdx.x < off) sm[threadIdx.x] += sm[threadIdx.x + off];
            __syncthreads();
        }
        if (threadIdx.x == 0) part[pb] = sm[0];
    }
}

// ---------------- fused rope-apply (q,k) + V transpose --------------------
__global__ void k_rope_vt(unsigned short* __restrict__ qkv, const float* __restrict__ tab,
                          unsigned short* __restrict__ vtg) {
    const int bid = blockIdx.x;
    if (bid < 6144) {
        int i = bid * 256 + threadIdx.x;          // NTOK*H*32
        int j  = i & 31;
        int h  = (i >> 5) % HH;
        int bt = i / (32 * HH);
        int t  = bt & (TT - 1);
        float cs = tab[(t*32 + j)*2];
        float sn = tab[(t*32 + j)*2 + 1];
        size_t base = (size_t)bt * (3*CC) + h * SS + 2*j;
        unsigned q = *(unsigned*)(qkv + base);
        float qe = bfl(q), qo = bfh(q);
        *(unsigned*)(qkv + base) = pk2(qe*cs - qo*sn, qo*cs + qe*sn);
        unsigned k = *(unsigned*)(qkv + base + CC);
        float ke = bfl(k), ko = bfh(k);
        *(unsigned*)(qkv + base + CC) = pk2(ke*cs - ko*sn, ko*cs + ke*sn);
    } else {
        int b2 = bid - 6144;                      // 384 blocks: bh 0..47, ty 0..7
        int bh = b2 >> 3, ty = b2 & 7;
        int b = bh / HH, h = bh % HH;
        int d = threadIdx.x & 63, tq = threadIdx.x >> 6;
        int t0 = ty * 128 + tq * 32;
        const unsigned short* src = qkv + (size_t)(b*TT + t0)*(3*CC) + 2*CC + h*SS + d;
        unsigned v[16];
#pragma unroll
        for (int e = 0; e < 16; ++e) {
            unsigned lo = src[(size_t)(2*e)*(3*CC)];
            unsigned hi = src[(size_t)(2*e+1)*(3*CC)];
            v[e] = (lo & 0xFFFFu) | (hi << 16);
        }
        uint4* dst = (uint4*)(vtg + ((size_t)bh*64 + d)*TT + t0);
#pragma unroll
        for (int q = 0; q < 4; ++q)
            dst[q] = make_uint4(v[q*4], v[q*4+1], v[q*4+2], v[q*4+3]);
    }
}

// ---------------- 128x128 bf16 MFMA GEMM (2-phase) — small-N cases --------
template<bool BIAS, bool RES, bool OUTB, bool SSQ>
__global__ __launch_bounds__(256) void k_gemm_bf16(
    const unsigned short* __restrict__ A, const unsigned short* __restrict__ Bt,
    const float* __restrict__ bias, const float* __restrict__ res,
    void* __restrict__ Cv, int M, int N, int K, float* __restrict__ ssq_part)
{
    __shared__ unsigned short As[2][128*32];
    __shared__ unsigned short Bs[2][128*32];
    __shared__ float smr[256];
    const int tid  = threadIdx.x;
    const int w    = tid >> 6, lane = tid & 63;
    const int wr   = w >> 1,  wc   = w & 1;
    const int row0 = blockIdx.y * 128, col0 = blockIdx.x * 128;

    f32x4 acc[4][4];
#pragma unroll
    for (int m = 0; m < 4; ++m)
#pragma unroll
        for (int n = 0; n < 4; ++n) acc[m][n] = (f32x4){0.f, 0.f, 0.f, 0.f};

    const int lr4 = lane >> 2;
    const int scb = lane & 3;

    auto stage = [&](int t, int buf) {
#pragma unroll
        for (int i = 0; i < 2; ++i) {
            int lr = w * 32 + i * 16 + lr4;
            int cbs = scb ^ ((lr >> 1) & 3);
            const unsigned short* ga = A + (size_t)(row0 + lr) * K + t * 32 + cbs * 8;
            gload_lds16(ga, &As[buf][(w * 32 + i * 16) * 32]);
            const unsigned short* gb = Bt + (size_t)(col0 + lr) * K + t * 32 + cbs * 8;
            gload_lds16(gb, &Bs[buf][(w * 32 + i * 16) * 32]);
        }
    };

    const int nt = K / 32;
    stage(0, 0);
    int cur = 0;
    const int fr = lane & 15, fq = lane >> 4;
    for (int t = 0; t < nt; ++t) {
        __syncthreads();
        if (t + 1 < nt) stage(t + 1, cur ^ 1);
        bf16x8 af[4], bf[4];
#pragma unroll
        for (int m = 0; m < 4; ++m) {
            int ra = wr * 64 + m * 16 + fr;
            af[m] = *(const bf16x8*)&As[cur][ra * 32 + (fq ^ ((ra >> 1) & 3)) * 8];
            int rb = wc * 64 + m * 16 + fr;
            bf[m] = *(const bf16x8*)&Bs[cur][rb * 32 + (fq ^ ((rb >> 1) & 3)) * 8];
        }
#pragma unroll
        for (int m = 0; m < 4; ++m)
#pragma unroll
            for (int n = 0; n < 4; ++n)
                acc[m][n] = __builtin_amdgcn_mfma_f32_16x16x32_bf16(af[m], bf[n], acc[m][n], 0, 0, 0);
        cur ^= 1;
    }

    float ssq = 0.f;
#pragma unroll
    for (int m = 0; m < 4; ++m) {
#pragma unroll
        for (int n = 0; n < 4; ++n) {
            int col = col0 + wc * 64 + n * 16 + fr;
            float bv = BIAS ? bias[col] : 0.f;
#pragma unroll
            for (int j = 0; j < 4; ++j) {
                int row = row0 + wr * 64 + m * 16 + fq * 4 + j;
                size_t off = (size_t)row * N + col;
                float v = acc[m][n][j] + bv;
                if (RES) v += res[off];
                if (OUTB) ((unsigned short*)Cv)[off] = f2bf(v);
                else      ((float*)Cv)[off] = v;
                if (SSQ) ssq += v * v;
            }
        }
    }
    if (SSQ) {
        smr[tid] = ssq;
        __syncthreads();
        for (int off = 128; off > 0; off >>= 1) {
            if (tid < off) smr[tid] += smr[tid + off];
            __syncthreads();
        }
        if (tid == 0) ssq_part[blockIdx.y * gridDim.x + blockIdx.x] = smr[0];
    }
}

// ---------------- 256x256 bf16 MFMA GEMM — ring-4, 1-phase/K32 -------------
// R13 structure, minus the forced lgkmcnt(0) drain: ds_reads are plain C++
// loads, so the compiler inserts fine-grained lgkmcnt(N) before each MFMA —
// the LDS service of later frags overlaps the MFMA cluster. sched_barrier
// after stages pins issue order (reads -> stages -> MFMA). Counted vmcnt
// gate + end barrier unchanged (ring correctness). Lane-local SWIGLU.
#define GSTEP(s_, DOSTAGE, GATE)                                                  \
    {                                                                             \
        const int st_ = (s_) & 3;                                                 \
        const unsigned short* pa_ = &ringA[st_][0];                               \
        const unsigned short* pb_ = &ringB[st_][0];                               \
        bf16x8 af[8], bv[4];                                                      \
        _Pragma("unroll")                                                         \
        for (int m = 0; m < 8; ++m)                                               \
            af[m] = *(const bf16x8*)&pa_[offA[m]];                                \
        _Pragma("unroll")                                                         \
        for (int n = 0; n < 4; ++n)                                               \
            bv[n] = *(const bf16x8*)&pb_[offB[n]];                                \
        if (DOSTAGE) { stageA((s_) + 3); stageB((s_) + 3); }                      \
        __builtin_amdgcn_sched_barrier(0);                                        \
        __builtin_amdgcn_s_setprio(1);                                            \
        _Pragma("unroll")                                                         \
        for (int m = 0; m < 8; ++m)                                               \
            _Pragma("unroll")                                                     \
            for (int n = 0; n < 4; ++n)                                           \
                acc[m][n] = __builtin_amdgcn_mfma_f32_16x16x32_bf16(              \
                    af[m], bv[n], acc[m][n], 0, 0, 0);                            \
        __builtin_amdgcn_s_setprio(0);                                            \
        asm volatile("s_waitcnt " GATE ::: "memory");                             \
        __builtin_amdgcn_sched_barrier(0);                                        \
        __builtin_amdgcn_s_barrier();                                             \
    }

template<bool BIAS, bool SWIGLU>
__global__ __launch_bounds__(512, 2) void k_gemm256(
    const unsigned short* __restrict__ A, const unsigned short* __restrict__ Bt,
    const float* __restrict__ bias, unsigned short* __restrict__ C,
    int M, int N, int K)
{
    __shared__ __align__(16) unsigned short ringA[4][256*32];
    __shared__ __align__(16) unsigned short ringB[4][256*32];
    const int tid = threadIdx.x;
    const int w = tid >> 6, lane = tid & 63;
    const int wm = w >> 2, wn = w & 3;
    const int fr = lane & 15, fq = lane >> 4;

    // XCD-bijective swizzle (all grids have nwg % 8 == 0)
    const int nwg = gridDim.x * gridDim.y;
    const int bid = blockIdx.y * gridDim.x + blockIdx.x;
    const int cpx = nwg >> 3;
    const int sbid = (bid & 7) * cpx + (bid >> 3);
    const int row0 = (sbid / gridDim.x) * 256;
    const int col0 = (sbid % gridDim.x) * 256;

    f32x4 acc[8][4];
#pragma unroll
    for (int m = 0; m < 8; ++m)
#pragma unroll
        for (int n = 0; n < 4; ++n) acc[m][n] = (f32x4){0.f, 0.f, 0.f, 0.f};

    // hoisted stage source pointers (only kb = t*32 varies)
    const int c0 = tid, c1 = 512 + tid;
    const int r0 = c0 >> 2, p0 = ((c0 & 3) ^ ((r0 >> 1) & 3)) * 8;
    const int r1 = c1 >> 2, p1 = ((c1 & 3) ^ ((r1 >> 1) & 3)) * 8;
    const unsigned short* aS0 = A  + (size_t)(row0 + r0) * K + p0;
    const unsigned short* aS1 = A  + (size_t)(row0 + r1) * K + p1;
    const unsigned short* bS0 = Bt + (size_t)(col0 + r0) * K + p0;
    const unsigned short* bS1 = Bt + (size_t)(col0 + r1) * K + p1;
    const int dL = w * 512;            // LDS dst offset (elements), q=0
    auto stageA = [&](int t) {
        const int st = t & 3;
        const int kb = t * 32;
        gload_lds16(aS0 + kb, &ringA[st][dL]);
        gload_lds16(aS1 + kb, &ringA[st][4096 + dL]);
    };
    auto stageB = [&](int t) {
        const int st = t & 3;
        const int kb = t * 32;
        gload_lds16(bS0 + kb, &ringB[st][dL]);
        gload_lds16(bS1 + kb, &ringB[st][4096 + dL]);
    };

    // hoisted frag read offsets
    int offA[8], offB[4];
#pragma unroll
    for (int m = 0; m < 8; ++m) {
        int ra = wm*128 + m*16 + fr;
        offA[m] = ra*32 + (fq ^ ((ra >> 1) & 3))*8;
    }
#pragma unroll
    for (int n = 0; n < 4; ++n) {
        int rb = wn*64 + n*16 + fr;
        offB[n] = rb*32 + (fq ^ ((rb >> 1) & 3))*8;
    }

    const int S = K >> 5;     // k32 steps
    stageA(0); stageB(0); stageA(1); stageB(1); stageA(2); stageB(2);
    asm volatile("s_waitcnt vmcnt(8)" ::: "memory");
    __builtin_amdgcn_s_barrier();
    int s = 0;
    for (; s < S - 3; ++s) GSTEP(s, true, "vmcnt(8)");
    GSTEP(s, false, "vmcnt(4)"); ++s;
    GSTEP(s, false, "vmcnt(0)"); ++s;
    GSTEP(s, false, "vmcnt(0)");

    // epilogue: row = wm*128 + m*16 + fq*4 + j, col = wn*64 + n*16 + fr
    if (SWIGLU) {
#pragma unroll
        for (int m = 0; m < 8; ++m) {
#pragma unroll
            for (int n = 0; n < 4; n += 2) {
                int colw = col0 + wn*64 + n*16 + fr;       // packed wx col
                float bw_ = BIAS ? bias[colw] : 0.f;
                float bg_ = BIAS ? bias[colw + 16] : 0.f;
                int colo = ((colw >> 5) << 4) + (colw & 15); // logical out col
#pragma unroll
                for (int j = 0; j < 4; ++j) {
                    int row = row0 + wm*128 + m*16 + fq*4 + j;
                    float wx = acc[m][n][j] + bw_;
                    float vx = acc[m][n+1][j] + bg_;
                    float sw = wx * vx / (1.f + __expf(-vx));
                    C[(size_t)row * (N >> 1) + colo] = f2bf(sw);
                }
            }
        }
    } else {
#pragma unroll
        for (int m = 0; m < 8; ++m) {
#pragma unroll
            for (int n = 0; n < 4; ++n) {
                int col = col0 + wn*64 + n*16 + fr;
                float bvb = BIAS ? bias[col] : 0.f;
#pragma unroll
                for (int j = 0; j < 4; ++j) {
                    int row = row0 + wm*128 + m*16 + fq*4 + j;
                    C[(size_t)row * N + col] = f2bf(acc[m][n][j] + bvb);
                }
            }
        }
    }
}

// ---------------- MFMA flash attention (causal), bf16 --------------------
__global__ __launch_bounds__(256) void k_attn_mfma(
    const unsigned short* __restrict__ qkv, const unsigned short* __restrict__ vtg,
    unsigned short* __restrict__ attn)
{
    __shared__ __align__(16) unsigned short Ks[2][64*64];
    __shared__ __align__(16) unsigned short Vs[2][64*64];
    __shared__ __align__(16) unsigned short Ps[4][16*72];
    const int tid = threadIdx.x;
    const int w = tid >> 6, lane = tid & 63;
    const int fr = lane & 15, fq = lane >> 4;
    const int bh = blockIdx.x, b = bh / HH, h = bh % HH;
    const int qb = blockIdx.y * 64;
    const int nkt = qb / 64 + 1;
    const float scale = 0.03608439182435161f;  // 768^-0.5

    bf16x8 qf[2];
    {
        const unsigned short* qp = qkv + (size_t)(b*TT + qb + w*16 + fr)*(3*CC) + h*SS + fq*8;
        qf[0] = *(const bf16x8*)qp;
        qf[1] = *(const bf16x8*)(qp + 32);
    }

    auto stage = [&](int kt, int buf) {
        const unsigned short* kbase = qkv + (size_t)(b*TT + kt*64)*(3*CC) + CC + h*SS;
        const unsigned short* vbase = vtg + ((size_t)bh*64)*TT + kt*64;
#pragma unroll
        for (int p = 0; p < 2; ++p) {
            int s = p*256 + tid;
            int row = s >> 3;
            int blk = (s & 7) ^ (row & 7);
            gload_lds16(kbase + (size_t)row*(3*CC) + blk*8, &Ks[buf][(p*256 + w*64)*8]);
            gload_lds16(vbase + (size_t)row*TT + blk*8,     &Vs[buf][(p*256 + w*64)*8]);
        }
    };

    float m[4] = {-INFINITY, -INFINITY, -INFINITY, -INFINITY};
    float l[4] = {0.f, 0.f, 0.f, 0.f};
    f32x4 oacc[4];
#pragma unroll
    for (int n = 0; n < 4; ++n) oacc[n] = (f32x4){0.f, 0.f, 0.f, 0.f};

    stage(0, 0);
    int cur = 0;
    for (int kt = 0; kt < nkt; ++kt) {
        __syncthreads();
        if (kt + 1 < nkt) stage(kt + 1, cur ^ 1);

        f32x4 sacc[4];
#pragma unroll
        for (int n = 0; n < 4; ++n) sacc[n] = (f32x4){0.f, 0.f, 0.f, 0.f};
#pragma unroll
        for (int ks = 0; ks < 2; ++ks) {
#pragma unroll
            for (int n = 0; n < 4; ++n) {
                int row = n*16 + fr;
                bf16x8 kf = *(const bf16x8*)&Ks[cur][row*64 + ((ks*4 + fq) ^ (row & 7))*8];
                sacc[n] = __builtin_amdgcn_mfma_f32_16x16x32_bf16(qf[ks], kf, sacc[n], 0, 0, 0);
            }
        }

        float sv[4][4];
        const bool lastt = (kt == nkt - 1);
        const int qloc = w*16 + fq*4;
#pragma unroll
        for (int n = 0; n < 4; ++n) {
            int kloc = n*16 + fr;
#pragma unroll
            for (int j = 0; j < 4; ++j) {
                float vv = sacc[n][j] * scale;
                if (lastt && kloc > qloc + j) vv = -INFINITY;
                sv[j][n] = vv;
            }
        }
        float mx[4], ls[4];
#pragma unroll
        for (int j = 0; j < 4; ++j)
            mx[j] = fmaxf(fmaxf(sv[j][0], sv[j][1]), fmaxf(sv[j][2], sv[j][3]));
#pragma unroll
        for (int d = 1; d < 16; d <<= 1)
#pragma unroll
            for (int j = 0; j < 4; ++j) mx[j] = fmaxf(mx[j], __shfl_xor(mx[j], d));
        float corr[4];
#pragma unroll
        for (int j = 0; j < 4; ++j) {
            float nm = fmaxf(m[j], mx[j]);
            corr[j] = __expf(m[j] - nm);
            m[j] = nm;
        }
#pragma unroll
        for (int j = 0; j < 4; ++j) {
            float s0 = 0.f;
#pragma unroll
            for (int n = 0; n < 4; ++n) {
                float p = __expf(sv[j][n] - m[j]);
                sv[j][n] = p;
                s0 += p;
            }
            ls[j] = s0;
        }
#pragma unroll
        for (int d = 1; d < 16; d <<= 1)
#pragma unroll
            for (int j = 0; j < 4; ++j) ls[j] += __shfl_xor(ls[j], d);
#pragma unroll
        for (int j = 0; j < 4; ++j) l[j] = l[j]*corr[j] + ls[j];
#pragma unroll
        for (int n = 0; n < 4; ++n)
#pragma unroll
            for (int j = 0; j < 4; ++j) oacc[n][j] *= corr[j];

#pragma unroll
        for (int j = 0; j < 4; ++j)
#pragma unroll
            for (int n = 0; n < 4; ++n)
                Ps[w][(fq*4 + j)*72 + n*16 + fr] = f2bf(sv[j][n]);

#pragma unroll
        for (int ks = 0; ks < 2; ++ks) {
            bf16x8 pf = *(const bf16x8*)&Ps[w][fr*72 + ks*32 + fq*8];
#pragma unroll
            for (int n = 0; n < 4; ++n) {
                int row = n*16 + fr;
                bf16x8 vf = *(const bf16x8*)&Vs[cur][row*64 + ((ks*4 + fq) ^ (row & 7))*8];
                oacc[n] = __builtin_amdgcn_mfma_f32_16x16x32_bf16(pf, vf, oacc[n], 0, 0, 0);
            }
        }
        cur ^= 1;
    }

    float inv[4];
#pragma unroll
    for (int j = 0; j < 4; ++j) inv[j] = 1.0f / l[j];
#pragma unroll
    for (int n = 0; n < 4; ++n)
#pragma unroll
        for (int j = 0; j < 4; ++j) {
            size_t off = (size_t)(b*TT + qb + w*16 + fq*4 + j)*CC + h*SS + n*16 + fr;
            attn[off] = f2bf(oacc[n][j] * inv[j]);
        }
}

// ---------------- launch ---------------------------------------------------
extern "C" void kernel_launch(void* const* d_in, const int* in_sizes, int n_in,
                              void* d_out, int out_size, void* d_ws, size_t ws_size,
                              hipStream_t stream)
{
    const float* x  = (const float*)d_in[0];
    const float* Wq = (const float*)d_in[1];
    const float* Wk = (const float*)d_in[2];
    const float* Wv = (const float*)d_in[3];
    const float* Wo = (const float*)d_in[4];
    const float* g1 = (const float*)d_in[5];
    const float* g2 = (const float*)d_in[6];
    const float* W1 = (const float*)d_in[7];
    const float* b1 = (const float*)d_in[8];
    const float* Ww = (const float*)d_in[9];
    const float* bw = (const float*)d_in[10];
    const float* Wg = (const float*)d_in[11];
    const float* bg = (const float*)d_in[12];
    const float* Wd = (const float*)d_in[13];
    const float* bd = (const float*)d_in[14];
    const float* W2 = (const float*)d_in[15];
    const float* b2 = (const float*)d_in[16];
    float* out = (float*)d_out;

    char* p = (char*)d_ws;
    auto alloc = [&](size_t bytes) { char* r = p; p += (bytes + 255) & ~(size_t)255; return r; };

    float*          part   = (float*)alloc(4096);
    float*          tab    = (float*)alloc((size_t)TT*32*2*4);
    float*          bcat   = (float*)alloc((size_t)2*HIDD*4);
    unsigned short* hb     = (unsigned short*)alloc((size_t)NTOK*CC*2);
    unsigned short* wqkvT  = (unsigned short*)alloc((size_t)3*CC*CC*2);
    unsigned short* qkvb   = (unsigned short*)alloc((size_t)NTOK*3*CC*2);
    unsigned short* vtg    = (unsigned short*)alloc((size_t)BB*HH*SS*TT*2);
    unsigned short* attnb  = (unsigned short*)alloc((size_t)NTOK*CC*2);
    unsigned short* WoT    = (unsigned short*)alloc((size_t)CC*CC*2);
    unsigned short* W1T    = (unsigned short*)alloc((size_t)FFD*CC*2);
    unsigned short* ub     = (unsigned short*)alloc((size_t)NTOK*FFD*2);
    unsigned short* WcatT  = (unsigned short*)alloc((size_t)2*HIDD*FFD*2);
    unsigned short* swb    = (unsigned short*)alloc((size_t)NTOK*HIDD*2);
    unsigned short* WdT    = (unsigned short*)alloc((size_t)FFD*HIDD*2);
    unsigned short* W2T    = (unsigned short*)alloc((size_t)CC*FFD*2);

    const int n = NTOK * CC;

    // fused weight prep + rms1 sumsq
    k_prep<<<J9, 256, 0, stream>>>(Wq, Wk, Wv, Wo, W1, Ww, Wg, Wd, W2, bw, bg, x,
                                   wqkvT, WoT, W1T, WcatT, WdT, W2T, bcat, tab, part);

    // rms1 -> h (bf16)
    k_scale_gamma_b<<<(n/8)/256, 256, 0, stream>>>(x, g1, part, hb, n/8,
                                                   1.0f/(float)n, JSUM);

    // qkv = h @ WqkvT^T  (ring4 256^2)
    k_gemm256<false,false><<<dim3(3*CC/256, NTOK/256), 512, 0, stream>>>(
        hb, wqkvT, nullptr, qkvb, NTOK, 3*CC, CC);
    // rope(q,k) + V transpose (fused)
    k_rope_vt<<<6144 + 384, 256, 0, stream>>>(qkvb, tab, vtg);

    // attention (MFMA)
    k_attn_mfma<<<dim3(BB*HH, TT/64), 256, 0, stream>>>(qkvb, vtg, attnb);

    // out1 = attn @ Wo + x  (128^2, fp32 out) + fused rms2 sumsq partials
    k_gemm_bf16<false,true,false,true><<<dim3(CC/128, NTOK/128), 256, 0, stream>>>(
        attnb, WoT, nullptr, x, out, NTOK, CC, CC, part);

    // rms2 -> h2 (reduces 192 partials from Wo epilogue)
    k_scale_gamma_b<<<(n/8)/256, 256, 0, stream>>>(out, g2, part, hb, n/8,
                                                   1.0f/(float)n, (CC/128)*(NTOK/128));

    // u = h2 @ W1 + b1  (ring4)
    k_gemm256<true,false><<<dim3(FFD/256, NTOK/256), 512, 0, stream>>>(
        hb, W1T, b1, ub, NTOK, FFD, CC);
    // swb = swiglu(u @ WcatT + bcat)  (lane-local fused epilogue, ring4)
    k_gemm256<true,true><<<dim3(2*HIDD/256, NTOK/256), 512, 0, stream>>>(
        ub, WcatT, bcat, swb, NTOK, 2*HIDD, FFD);
    // ffmid = sw @ Wd + bd  (ring4)
    k_gemm256<true,false><<<dim3(FFD/256, NTOK/256), 512, 0, stream>>>(
        swb, WdT, bd, ub, NTOK, FFD, HIDD);
    // out = out1 + ffmid @ W2 + b2  (128^2, fp32 out + residual)
    k_gemm_bf16<true,true,false,false><<<dim3(CC/128, NTOK/128), 256, 0, stream>>>(
        ub, W2T, b2, out, out, NTOK, CC, FFD, nullptr);
}

// Round 16
// 370.552 us; speedup vs baseline: 1.0867x; 1.0215x over previous
//
#include <hip/hip_runtime.h>
#include <math.h>

#define BB   4
#define TT   1024
#define CC   768
#define HH   12
#define SS   64
#define FFD  3072
#define HIDD 2048
#define NTOK (BB*TT)          // 4096
#define EPSR 1e-6f

typedef __attribute__((ext_vector_type(8))) short bf16x8;
typedef __attribute__((ext_vector_type(4))) float f32x4;

__device__ __forceinline__ unsigned short f2bf(float f) {
    unsigned u = __float_as_uint(f);
    return (unsigned short)((u + 0x7FFFu + ((u >> 16) & 1u)) >> 16);
}
__device__ __forceinline__ float bfl(unsigned u) { return __uint_as_float(u << 16); }
__device__ __forceinline__ float bfh(unsigned u) { return __uint_as_float(u & 0xFFFF0000u); }
__device__ __forceinline__ unsigned pk2(float a, float b) {
    return (unsigned)f2bf(a) | ((unsigned)f2bf(b) << 16);
}

__device__ __forceinline__ void gload_lds16(const unsigned short* g, unsigned short* l) {
    __builtin_amdgcn_global_load_lds(
        (const __attribute__((address_space(1))) unsigned int*)g,
        (__attribute__((address_space(3))) unsigned int*)l, 16, 0, 0);
}

// ---------------- h_bf16 = bf16(x * rms_scale * gamma[c]) ------------------
__global__ void k_scale_gamma_b(const float* __restrict__ x, const float* __restrict__ g,
                                const float* __restrict__ part, unsigned short* __restrict__ h,
                                int n8, float invn, int npart) {
    __shared__ float sm[256];
    float s = 0.f;
    for (int i = threadIdx.x; i < npart; i += 256) s += part[i];
    sm[threadIdx.x] = s;
    __syncthreads();
    for (int off = 128; off > 0; off >>= 1) {
        if (threadIdx.x < off) sm[threadIdx.x] += sm[threadIdx.x + off];
        __syncthreads();
    }
    float sc = 1.0f / sqrtf(EPSR + sm[0] * invn);
    int i = blockIdx.x * blockDim.x + threadIdx.x;
    if (i >= n8) return;
    float4 v0 = ((const float4*)x)[2*i];
    float4 v1 = ((const float4*)x)[2*i+1];
    int c = (i * 8) % CC;
    float4 g0 = *(const float4*)(g + c);
    float4 g1v = *(const float4*)(g + c + 4);
    uint4 r;
    r.x = pk2(v0.x*sc*g0.x,  v0.y*sc*g0.y);
    r.y = pk2(v0.z*sc*g0.z,  v0.w*sc*g0.w);
    r.z = pk2(v1.x*sc*g1v.x, v1.y*sc*g1v.y);
    r.w = pk2(v1.z*sc*g1v.z, v1.w*sc*g1v.w);
    ((uint4*)h)[i] = r;
}

// ---------------- fused weight prep + rms1 sumsq ---------------------------
#define TQKV 1728
#define TWO  576
#define TW1  2304
#define TWW  6144
#define TWD  6144
#define TW2  2304
#define J0 (TQKV)
#define J1 (J0 + TWO)
#define J2 (J1 + TW1)
#define J3 (J2 + TWW)
#define J4 (J3 + TWW)
#define J5 (J4 + TWD)
#define J6 (J5 + TW2)
#define J7 (J6 + 16)
#define J8 (J7 + 128)
#define JSUM 1024
#define J9 (J8 + JSUM)

__device__ __forceinline__ void wT_tile(float (*tl)[33], const float* __restrict__ W,
                                        unsigned short* __restrict__ Wt,
                                        int K, int N, int t, int tx, int ty) {
    int nk = K >> 5;
    int k0 = (t % nk) * 32, n0 = (t / nk) * 32;
#pragma unroll
    for (int i = 0; i < 4; ++i)
        tl[ty + i*8][tx] = W[(size_t)(k0 + ty + i*8) * N + n0 + tx];
    __syncthreads();
#pragma unroll
    for (int i = 0; i < 4; ++i)
        Wt[(size_t)(n0 + ty + i*8) * K + k0 + tx] = f2bf(tl[tx][ty + i*8]);
}

// 16-block interleave: logical col j -> packed row (j&~15)*2 + ofs*16 + (j&15)
__device__ __forceinline__ void wT_tile_il(float (*tl)[33], const float* __restrict__ W,
                                           unsigned short* __restrict__ Wt,
                                           int K, int N, int t, int tx, int ty, int ofs) {
    int nk = K >> 5;
    int k0 = (t % nk) * 32, n0 = (t / nk) * 32;
#pragma unroll
    for (int i = 0; i < 4; ++i)
        tl[ty + i*8][tx] = W[(size_t)(k0 + ty + i*8) * N + n0 + tx];
    __syncthreads();
#pragma unroll
    for (int i = 0; i < 4; ++i) {
        int j = n0 + ty + i*8;
        int pr = ((j & ~15) << 1) + ofs*16 + (j & 15);
        Wt[(size_t)pr * K + k0 + tx] = f2bf(tl[tx][ty + i*8]);
    }
}

__global__ void k_prep(const float* __restrict__ Wq, const float* __restrict__ Wk,
                       const float* __restrict__ Wv, const float* __restrict__ Wo,
                       const float* __restrict__ W1, const float* __restrict__ Ww,
                       const float* __restrict__ Wg, const float* __restrict__ Wd,
                       const float* __restrict__ W2, const float* __restrict__ bw,
                       const float* __restrict__ bg, const float* __restrict__ x,
                       unsigned short* __restrict__ wqkvT, unsigned short* __restrict__ WoT,
                       unsigned short* __restrict__ W1T, unsigned short* __restrict__ WcatT,
                       unsigned short* __restrict__ WdT, unsigned short* __restrict__ W2T,
                       float* __restrict__ bcat, float* __restrict__ tab,
                       float* __restrict__ part) {
    __shared__ float tl[32][33];
    const int bid = blockIdx.x;
    const int tx = threadIdx.x & 31, ty = threadIdx.x >> 5;
    if (bid < J0) {
        int t = bid;
        int c0 = (t % 24) * 32;
        int s0 = ((t / 24) & 1) * 32;
        int z = t / 48, sel = z / HH, h = z % HH;
        const float* W = (sel == 0 ? Wq : (sel == 1 ? Wk : Wv)) + (size_t)h * CC * SS;
#pragma unroll
        for (int i = 0; i < 4; ++i)
            tl[ty + i*8][tx] = W[(size_t)(c0 + ty + i*8) * SS + s0 + tx];
        __syncthreads();
#pragma unroll
        for (int i = 0; i < 4; ++i) {
            int s = s0 + ty + i*8;
            int r;
            if (sel < 2) {                      // Q/K: rope-pair 16-block interleave
                int gp = h*32 + (s >> 1);       // global pair index
                r = (gp >> 4)*32 + ((s & 1) << 4) + (gp & 15);
            } else {
                r = h*SS + s;                   // V: plain layout
            }
            wqkvT[(size_t)(sel*CC + r) * CC + c0 + tx] = f2bf(tl[tx][ty + i*8]);
        }
    } else if (bid < J1) {
        wT_tile(tl, Wo, WoT, CC, CC, bid - J0, tx, ty);
    } else if (bid < J2) {
        wT_tile(tl, W1, W1T, CC, FFD, bid - J1, tx, ty);
    } else if (bid < J3) {
        wT_tile_il(tl, Ww, WcatT, FFD, HIDD, bid - J2, tx, ty, 0);
    } else if (bid < J4) {
        wT_tile_il(tl, Wg, WcatT, FFD, HIDD, bid - J3, tx, ty, 1);
    } else if (bid < J5) {
        wT_tile(tl, Wd, WdT, HIDD, FFD, bid - J4, tx, ty);
    } else if (bid < J6) {
        wT_tile(tl, W2, W2T, FFD, CC, bid - J5, tx, ty);
    } else if (bid < J7) {
        int ip = (bid - J6) * 256 + threadIdx.x;   // packed index in [0,4096)
        int lg = ((ip >> 5) << 4) + (ip & 15);     // logical col
        bcat[ip] = ((ip >> 4) & 1) ? bg[lg] : bw[lg];
    } else if (bid < J8) {
        int i = (bid - J7) * 256 + threadIdx.x;   // T*32
        int t = i >> 5, j = i & 31;
        float th = expf(-(float)j * 0.5756462732485115f);  // 10000^(-j/16)
        float ang = (float)t * th;
        tab[2*i]   = cosf(ang);
        tab[2*i+1] = sinf(ang);
    } else {
        float* sm = &tl[0][0];
        const int pb = bid - J8;
        const int n4 = NTOK * CC / 4;
        float s = 0.f;
        int stride = JSUM * 256;
        for (int i = pb * 256 + threadIdx.x; i < n4; i += stride) {
            float4 v = ((const float4*)x)[i];
            s += v.x*v.x + v.y*v.y + v.z*v.z + v.w*v.w;
        }
        sm[threadIdx.x] = s;
        __syncthreads();
        for (int off = 128; off > 0; off >>= 1) {
            if (threadIdx.x < off) sm[threadIdx.x] += sm[threadIdx.x + off];
            __syncthreads();
        }
        if (threadIdx.x == 0) part[pb] = sm[0];
    }
}

// ---------------- 128x128 bf16 MFMA GEMM (2-phase) — small-N cases --------
template<bool BIAS, bool RES, bool OUTB, bool SSQ>
__global__ __launch_bounds__(256) void k_gemm_bf16(
    const unsigned short* __restrict__ A, const unsigned short* __restrict__ Bt,
    const float* __restrict__ bias, const float* __restrict__ res,
    void* __restrict__ Cv, int M, int N, int K, float* __restrict__ ssq_part)
{
    __shared__ unsigned short As[2][128*32];
    __shared__ unsigned short Bs[2][128*32];
    __shared__ float smr[256];
    const int tid  = threadIdx.x;
    const int w    = tid >> 6, lane = tid & 63;
    const int wr   = w >> 1,  wc   = w & 1;
    const int row0 = blockIdx.y * 128, col0 = blockIdx.x * 128;

    f32x4 acc[4][4];
#pragma unroll
    for (int m = 0; m < 4; ++m)
#pragma unroll
        for (int n = 0; n < 4; ++n) acc[m][n] = (f32x4){0.f, 0.f, 0.f, 0.f};

    const int lr4 = lane >> 2;
    const int scb = lane & 3;

    auto stage = [&](int t, int buf) {
#pragma unroll
        for (int i = 0; i < 2; ++i) {
            int lr = w * 32 + i * 16 + lr4;
            int cbs = scb ^ ((lr >> 1) & 3);
            const unsigned short* ga = A + (size_t)(row0 + lr) * K + t * 32 + cbs * 8;
            gload_lds16(ga, &As[buf][(w * 32 + i * 16) * 32]);
            const unsigned short* gb = Bt + (size_t)(col0 + lr) * K + t * 32 + cbs * 8;
            gload_lds16(gb, &Bs[buf][(w * 32 + i * 16) * 32]);
        }
    };

    const int nt = K / 32;
    stage(0, 0);
    int cur = 0;
    const int fr = lane & 15, fq = lane >> 4;
    for (int t = 0; t < nt; ++t) {
        __syncthreads();
        if (t + 1 < nt) stage(t + 1, cur ^ 1);
        bf16x8 af[4], bf[4];
#pragma unroll
        for (int m = 0; m < 4; ++m) {
            int ra = wr * 64 + m * 16 + fr;
            af[m] = *(const bf16x8*)&As[cur][ra * 32 + (fq ^ ((ra >> 1) & 3)) * 8];
            int rb = wc * 64 + m * 16 + fr;
            bf[m] = *(const bf16x8*)&Bs[cur][rb * 32 + (fq ^ ((rb >> 1) & 3)) * 8];
        }
#pragma unroll
        for (int m = 0; m < 4; ++m)
#pragma unroll
            for (int n = 0; n < 4; ++n)
                acc[m][n] = __builtin_amdgcn_mfma_f32_16x16x32_bf16(af[m], bf[n], acc[m][n], 0, 0, 0);
        cur ^= 1;
    }

    float ssq = 0.f;
#pragma unroll
    for (int m = 0; m < 4; ++m) {
#pragma unroll
        for (int n = 0; n < 4; ++n) {
            int col = col0 + wc * 64 + n * 16 + fr;
            float bv = BIAS ? bias[col] : 0.f;
#pragma unroll
            for (int j = 0; j < 4; ++j) {
                int row = row0 + wr * 64 + m * 16 + fq * 4 + j;
                size_t off = (size_t)row * N + col;
                float v = acc[m][n][j] + bv;
                if (RES) v += res[off];
                if (OUTB) ((unsigned short*)Cv)[off] = f2bf(v);
                else      ((float*)Cv)[off] = v;
                if (SSQ) ssq += v * v;
            }
        }
    }
    if (SSQ) {
        smr[tid] = ssq;
        __syncthreads();
        for (int off = 128; off > 0; off >>= 1) {
            if (tid < off) smr[tid] += smr[tid + off];
            __syncthreads();
        }
        if (tid == 0) ssq_part[blockIdx.y * gridDim.x + blockIdx.x] = smr[0];
    }
}

// ---------------- 256x256 bf16 MFMA GEMM — ring-4, 1-phase/K32 -------------
// Epilogue variants (all lane-local, block-uniform branches):
//  SWIGLU: 16-block interleaved wx/vx pairs -> swiglu, N/2 output.
//  QKV:    col0<1536 -> rope pairs (Q/K, pair-interleaved packing) written to
//          logical cols; col0>=1536 -> V stored transposed into vtg.
#define GSTEP(s_, DOSTAGE, GATE)                                                  \
    {                                                                             \
        const int st_ = (s_) & 3;                                                 \
        const unsigned short* pa_ = &ringA[st_][0];                               \
        const unsigned short* pb_ = &ringB[st_][0];                               \
        bf16x8 af[8], bv[4];                                                      \
        _Pragma("unroll")                                                         \
        for (int m = 0; m < 8; ++m)                                               \
            af[m] = *(const bf16x8*)&pa_[offA[m]];                                \
        _Pragma("unroll")                                                         \
        for (int n = 0; n < 4; ++n)                                               \
            bv[n] = *(const bf16x8*)&pb_[offB[n]];                                \
        if (DOSTAGE) { stageA((s_) + 3); stageB((s_) + 3); }                      \
        __builtin_amdgcn_sched_barrier(0);                                        \
        __builtin_amdgcn_s_setprio(1);                                            \
        _Pragma("unroll")                                                         \
        for (int m = 0; m < 8; ++m)                                               \
            _Pragma("unroll")                                                     \
            for (int n = 0; n < 4; ++n)                                           \
                acc[m][n] = __builtin_amdgcn_mfma_f32_16x16x32_bf16(              \
                    af[m], bv[n], acc[m][n], 0, 0, 0);                            \
        __builtin_amdgcn_s_setprio(0);                                            \
        asm volatile("s_waitcnt " GATE ::: "memory");                             \
        __builtin_amdgcn_sched_barrier(0);                                        \
        __builtin_amdgcn_s_barrier();                                             \
    }

template<bool BIAS, bool SWIGLU, bool QKV>
__global__ __launch_bounds__(512, 2) void k_gemm256(
    const unsigned short* __restrict__ A, const unsigned short* __restrict__ Bt,
    const float* __restrict__ bias, unsigned short* __restrict__ C,
    int M, int N, int K, const float* __restrict__ tab,
    unsigned short* __restrict__ vtg)
{
    __shared__ __align__(16) unsigned short ringA[4][256*32];
    __shared__ __align__(16) unsigned short ringB[4][256*32];
    const int tid = threadIdx.x;
    const int w = tid >> 6, lane = tid & 63;
    const int wm = w >> 2, wn = w & 3;
    const int fr = lane & 15, fq = lane >> 4;

    // XCD-bijective swizzle (all grids have nwg % 8 == 0)
    const int nwg = gridDim.x * gridDim.y;
    const int bid = blockIdx.y * gridDim.x + blockIdx.x;
    const int cpx = nwg >> 3;
    const int sbid = (bid & 7) * cpx + (bid >> 3);
    const int row0 = (sbid / gridDim.x) * 256;
    const int col0 = (sbid % gridDim.x) * 256;

    f32x4 acc[8][4];
#pragma unroll
    for (int m = 0; m < 8; ++m)
#pragma unroll
        for (int n = 0; n < 4; ++n) acc[m][n] = (f32x4){0.f, 0.f, 0.f, 0.f};

    // hoisted stage source pointers (only kb = t*32 varies)
    const int c0 = tid, c1 = 512 + tid;
    const int r0 = c0 >> 2, p0 = ((c0 & 3) ^ ((r0 >> 1) & 3)) * 8;
    const int r1 = c1 >> 2, p1 = ((c1 & 3) ^ ((r1 >> 1) & 3)) * 8;
    const unsigned short* aS0 = A  + (size_t)(row0 + r0) * K + p0;
    const unsigned short* aS1 = A  + (size_t)(row0 + r1) * K + p1;
    const unsigned short* bS0 = Bt + (size_t)(col0 + r0) * K + p0;
    const unsigned short* bS1 = Bt + (size_t)(col0 + r1) * K + p1;
    const int dL = w * 512;            // LDS dst offset (elements), q=0
    auto stageA = [&](int t) {
        const int st = t & 3;
        const int kb = t * 32;
        gload_lds16(aS0 + kb, &ringA[st][dL]);
        gload_lds16(aS1 + kb, &ringA[st][4096 + dL]);
    };
    auto stageB = [&](int t) {
        const int st = t & 3;
        const int kb = t * 32;
        gload_lds16(bS0 + kb, &ringB[st][dL]);
        gload_lds16(bS1 + kb, &ringB[st][4096 + dL]);
    };

    // hoisted frag read offsets
    int offA[8], offB[4];
#pragma unroll
    for (int m = 0; m < 8; ++m) {
        int ra = wm*128 + m*16 + fr;
        offA[m] = ra*32 + (fq ^ ((ra >> 1) & 3))*8;
    }
#pragma unroll
    for (int n = 0; n < 4; ++n) {
        int rb = wn*64 + n*16 + fr;
        offB[n] = rb*32 + (fq ^ ((rb >> 1) & 3))*8;
    }

    const int S = K >> 5;     // k32 steps
    stageA(0); stageB(0); stageA(1); stageB(1); stageA(2); stageB(2);
    asm volatile("s_waitcnt vmcnt(8)" ::: "memory");
    __builtin_amdgcn_s_barrier();
    int s = 0;
    for (; s < S - 3; ++s) GSTEP(s, true, "vmcnt(8)");
    GSTEP(s, false, "vmcnt(4)"); ++s;
    GSTEP(s, false, "vmcnt(0)"); ++s;
    GSTEP(s, false, "vmcnt(0)");

    // epilogue: row = wm*128 + m*16 + fq*4 + j, col = wn*64 + n*16 + fr
    if (QKV) {
        if (col0 < 1536) {
            // Q or K section: rope pairs (packed even col = acc[m][2np],
            // odd partner = acc[m][2np+1]); write to LOGICAL columns.
            const int sel = (col0 >= CC) ? 1 : 0;
#pragma unroll
            for (int m = 0; m < 8; ++m) {
#pragma unroll
                for (int np = 0; np < 2; ++np) {
                    int colw = col0 + wn*64 + np*32 + fr;     // even-parity packed col
                    int ps = colw - sel*CC;
                    int gp = (ps >> 5)*16 + (ps & 15);        // h*32 + j
                    int hh = gp >> 5, jj = gp & 31;
                    int ce = sel*CC + hh*64 + 2*jj;           // logical even col
#pragma unroll
                    for (int j = 0; j < 4; ++j) {
                        int row = row0 + wm*128 + m*16 + fq*4 + j;
                        int t = row & (TT - 1);
                        float cs = tab[(t*32 + jj)*2];
                        float sn = tab[(t*32 + jj)*2 + 1];
                        float e = acc[m][2*np][j];
                        float o = acc[m][2*np+1][j];
                        *(unsigned*)(C + (size_t)row * N + ce) =
                            pk2(e*cs - o*sn, o*cs + e*sn);
                    }
                }
            }
        } else {
            // V section: store transposed into vtg[bh][64][T]
            const int vb = row0 >> 10;                        // batch (block-uniform)
            const int tb = (row0 & (TT-1)) + wm*128;
#pragma unroll
            for (int m = 0; m < 8; ++m) {
#pragma unroll
                for (int n = 0; n < 4; ++n) {
                    int col = col0 + wn*64 + n*16 + fr;
                    int d = col - 1536;                       // h*64 + dd
                    int t0 = tb + m*16 + fq*4;
                    unsigned short* dst = vtg +
                        ((size_t)(vb*HH + (d >> 6))*64 + (d & 63))*TT + t0;
                    uint2 val;
                    val.x = pk2(acc[m][n][0], acc[m][n][1]);
                    val.y = pk2(acc[m][n][2], acc[m][n][3]);
                    *(uint2*)dst = val;
                }
            }
        }
    } else if (SWIGLU) {
#pragma unroll
        for (int m = 0; m < 8; ++m) {
#pragma unroll
            for (int n = 0; n < 4; n += 2) {
                int colw = col0 + wn*64 + n*16 + fr;       // packed wx col
                float bw_ = BIAS ? bias[colw] : 0.f;
                float bg_ = BIAS ? bias[colw + 16] : 0.f;
                int colo = ((colw >> 5) << 4) + (colw & 15); // logical out col
#pragma unroll
                for (int j = 0; j < 4; ++j) {
                    int row = row0 + wm*128 + m*16 + fq*4 + j;
                    float wx = acc[m][n][j] + bw_;
                    float vx = acc[m][n+1][j] + bg_;
                    float sw = wx * vx / (1.f + __expf(-vx));
                    C[(size_t)row * (N >> 1) + colo] = f2bf(sw);
                }
            }
        }
    } else {
#pragma unroll
        for (int m = 0; m < 8; ++m) {
#pragma unroll
            for (int n = 0; n < 4; ++n) {
                int col = col0 + wn*64 + n*16 + fr;
                float bvb = BIAS ? bias[col] : 0.f;
#pragma unroll
                for (int j = 0; j < 4; ++j) {
                    int row = row0 + wm*128 + m*16 + fq*4 + j;
                    C[(size_t)row * N + col] = f2bf(acc[m][n][j] + bvb);
                }
            }
        }
    }
}

// ---------------- MFMA flash attention (causal), bf16 --------------------
__global__ __launch_bounds__(256) void k_attn_mfma(
    const unsigned short* __restrict__ qkv, const unsigned short* __restrict__ vtg,
    unsigned short* __restrict__ attn)
{
    __shared__ __align__(16) unsigned short Ks[2][64*64];
    __shared__ __align__(16) unsigned short Vs[2][64*64];
    __shared__ __align__(16) unsigned short Ps[4][16*72];
    const int tid = threadIdx.x;
    const int w = tid >> 6, lane = tid & 63;
    const int fr = lane & 15, fq = lane >> 4;
    const int bh = blockIdx.x, b = bh / HH, h = bh % HH;
    const int qb = blockIdx.y * 64;
    const int nkt = qb / 64 + 1;
    const float scale = 0.03608439182435161f;  // 768^-0.5

    bf16x8 qf[2];
    {
        const unsigned short* qp = qkv + (size_t)(b*TT + qb + w*16 + fr)*(3*CC) + h*SS + fq*8;
        qf[0] = *(const bf16x8*)qp;
        qf[1] = *(const bf16x8*)(qp + 32);
    }

    auto stage = [&](int kt, int buf) {
        const unsigned short* kbase = qkv + (size_t)(b*TT + kt*64)*(3*CC) + CC + h*SS;
        const unsigned short* vbase = vtg + ((size_t)bh*64)*TT + kt*64;
#pragma unroll
        for (int p = 0; p < 2; ++p) {
            int s = p*256 + tid;
            int row = s >> 3;
            int blk = (s & 7) ^ (row & 7);
            gload_lds16(kbase + (size_t)row*(3*CC) + blk*8, &Ks[buf][(p*256 + w*64)*8]);
            gload_lds16(vbase + (size_t)row*TT + blk*8,     &Vs[buf][(p*256 + w*64)*8]);
        }
    };

    float m[4] = {-INFINITY, -INFINITY, -INFINITY, -INFINITY};
    float l[4] = {0.f, 0.f, 0.f, 0.f};
    f32x4 oacc[4];
#pragma unroll
    for (int n = 0; n < 4; ++n) oacc[n] = (f32x4){0.f, 0.f, 0.f, 0.f};

    stage(0, 0);
    int cur = 0;
    for (int kt = 0; kt < nkt; ++kt) {
        __syncthreads();
        if (kt + 1 < nkt) stage(kt + 1, cur ^ 1);

        f32x4 sacc[4];
#pragma unroll
        for (int n = 0; n < 4; ++n) sacc[n] = (f32x4){0.f, 0.f, 0.f, 0.f};
#pragma unroll
        for (int ks = 0; ks < 2; ++ks) {
#pragma unroll
            for (int n = 0; n < 4; ++n) {
                int row = n*16 + fr;
                bf16x8 kf = *(const bf16x8*)&Ks[cur][row*64 + ((ks*4 + fq) ^ (row & 7))*8];
                sacc[n] = __builtin_amdgcn_mfma_f32_16x16x32_bf16(qf[ks], kf, sacc[n], 0, 0, 0);
            }
        }

        float sv[4][4];
        const bool lastt = (kt == nkt - 1);
        const int qloc = w*16 + fq*4;
#pragma unroll
        for (int n = 0; n < 4; ++n) {
            int kloc = n*16 + fr;
#pragma unroll
            for (int j = 0; j < 4; ++j) {
                float vv = sacc[n][j] * scale;
                if (lastt && kloc > qloc + j) vv = -INFINITY;
                sv[j][n] = vv;
            }
        }
        float mx[4], ls[4];
#pragma unroll
        for (int j = 0; j < 4; ++j)
            mx[j] = fmaxf(fmaxf(sv[j][0], sv[j][1]), fmaxf(sv[j][2], sv[j][3]));
#pragma unroll
        for (int d = 1; d < 16; d <<= 1)
#pragma unroll
            for (int j = 0; j < 4; ++j) mx[j] = fmaxf(mx[j], __shfl_xor(mx[j], d));
        float corr[4];
#pragma unroll
        for (int j = 0; j < 4; ++j) {
            float nm = fmaxf(m[j], mx[j]);
            corr[j] = __expf(m[j] - nm);
            m[j] = nm;
        }
#pragma unroll
        for (int j = 0; j < 4; ++j) {
            float s0 = 0.f;
#pragma unroll
            for (int n = 0; n < 4; ++n) {
                float p = __expf(sv[j][n] - m[j]);
                sv[j][n] = p;
                s0 += p;
            }
            ls[j] = s0;
        }
#pragma unroll
        for (int d = 1; d < 16; d <<= 1)
#pragma unroll
            for (int j = 0; j < 4; ++j) ls[j] += __shfl_xor(ls[j], d);
#pragma unroll
        for (int j = 0; j < 4; ++j) l[j] = l[j]*corr[j] + ls[j];
#pragma unroll
        for (int n = 0; n < 4; ++n)
#pragma unroll
            for (int j = 0; j < 4; ++j) oacc[n][j] *= corr[j];

#pragma unroll
        for (int j = 0; j < 4; ++j)
#pragma unroll
            for (int n = 0; n < 4; ++n)
                Ps[w][(fq*4 + j)*72 + n*16 + fr] = f2bf(sv[j][n]);

#pragma unroll
        for (int ks = 0; ks < 2; ++ks) {
            bf16x8 pf = *(const bf16x8*)&Ps[w][fr*72 + ks*32 + fq*8];
#pragma unroll
            for (int n = 0; n < 4; ++n) {
                int row = n*16 + fr;
                bf16x8 vf = *(const bf16x8*)&Vs[cur][row*64 + ((ks*4 + fq) ^ (row & 7))*8];
                oacc[n] = __builtin_amdgcn_mfma_f32_16x16x32_bf16(pf, vf, oacc[n], 0, 0, 0);
            }
        }
        cur ^= 1;
    }

    float inv[4];
#pragma unroll
    for (int j = 0; j < 4; ++j) inv[j] = 1.0f / l[j];
#pragma unroll
    for (int n = 0; n < 4; ++n)
#pragma unroll
        for (int j = 0; j < 4; ++j) {
            size_t off = (size_t)(b*TT + qb + w*16 + fq*4 + j)*CC + h*SS + n*16 + fr;
            attn[off] = f2bf(oacc[n][j] * inv[j]);
        }
}

// ---------------- launch ---------------------------------------------------
extern "C" void kernel_launch(void* const* d_in, const int* in_sizes, int n_in,
                              void* d_out, int out_size, void* d_ws, size_t ws_size,
                              hipStream_t stream)
{
    const float* x  = (const float*)d_in[0];
    const float* Wq = (const float*)d_in[1];
    const float* Wk = (const float*)d_in[2];
    const float* Wv = (const float*)d_in[3];
    const float* Wo = (const float*)d_in[4];
    const float* g1 = (const float*)d_in[5];
    const float* g2 = (const float*)d_in[6];
    const float* W1 = (const float*)d_in[7];
    const float* b1 = (const float*)d_in[8];
    const float* Ww = (const float*)d_in[9];
    const float* bw = (const float*)d_in[10];
    const float* Wg = (const float*)d_in[11];
    const float* bg = (const float*)d_in[12];
    const float* Wd = (const float*)d_in[13];
    const float* bd = (const float*)d_in[14];
    const float* W2 = (const float*)d_in[15];
    const float* b2 = (const float*)d_in[16];
    float* out = (float*)d_out;

    char* p = (char*)d_ws;
    auto alloc = [&](size_t bytes) { char* r = p; p += (bytes + 255) & ~(size_t)255; return r; };

    float*          part   = (float*)alloc(4096);
    float*          tab    = (float*)alloc((size_t)TT*32*2*4);
    float*          bcat   = (float*)alloc((size_t)2*HIDD*4);
    unsigned short* hb     = (unsigned short*)alloc((size_t)NTOK*CC*2);
    unsigned short* wqkvT  = (unsigned short*)alloc((size_t)3*CC*CC*2);
    unsigned short* qkvb   = (unsigned short*)alloc((size_t)NTOK*3*CC*2);
    unsigned short* vtg    = (unsigned short*)alloc((size_t)BB*HH*SS*TT*2);
    unsigned short* attnb  = (unsigned short*)alloc((size_t)NTOK*CC*2);
    unsigned short* WoT    = (unsigned short*)alloc((size_t)CC*CC*2);
    unsigned short* W1T    = (unsigned short*)alloc((size_t)FFD*CC*2);
    unsigned short* ub     = (unsigned short*)alloc((size_t)NTOK*FFD*2);
    unsigned short* WcatT  = (unsigned short*)alloc((size_t)2*HIDD*FFD*2);
    unsigned short* swb    = (unsigned short*)alloc((size_t)NTOK*HIDD*2);
    unsigned short* WdT    = (unsigned short*)alloc((size_t)FFD*HIDD*2);
    unsigned short* W2T    = (unsigned short*)alloc((size_t)CC*FFD*2);

    const int n = NTOK * CC;

    // fused weight prep + rms1 sumsq
    k_prep<<<J9, 256, 0, stream>>>(Wq, Wk, Wv, Wo, W1, Ww, Wg, Wd, W2, bw, bg, x,
                                   wqkvT, WoT, W1T, WcatT, WdT, W2T, bcat, tab, part);

    // rms1 -> h (bf16)
    k_scale_gamma_b<<<(n/8)/256, 256, 0, stream>>>(x, g1, part, hb, n/8,
                                                   1.0f/(float)n, JSUM);

    // qkv = h @ WqkvT^T with fused rope(Q,K) + V-transpose epilogue
    k_gemm256<false,false,true><<<dim3(3*CC/256, NTOK/256), 512, 0, stream>>>(
        hb, wqkvT, nullptr, qkvb, NTOK, 3*CC, CC, tab, vtg);

    // attention (MFMA)
    k_attn_mfma<<<dim3(BB*HH, TT/64), 256, 0, stream>>>(qkvb, vtg, attnb);

    // out1 = attn @ Wo + x  (128^2, fp32 out) + fused rms2 sumsq partials
    k_gemm_bf16<false,true,false,true><<<dim3(CC/128, NTOK/128), 256, 0, stream>>>(
        attnb, WoT, nullptr, x, out, NTOK, CC, CC, part);

    // rms2 -> h2 (reduces 192 partials from Wo epilogue)
    k_scale_gamma_b<<<(n/8)/256, 256, 0, stream>>>(out, g2, part, hb, n/8,
                                                   1.0f/(float)n, (CC/128)*(NTOK/128));

    // u = h2 @ W1 + b1  (ring4)
    k_gemm256<true,false,false><<<dim3(FFD/256, NTOK/256), 512, 0, stream>>>(
        hb, W1T, b1, ub, NTOK, FFD, CC, nullptr, nullptr);
    // swb = swiglu(u @ WcatT + bcat)  (lane-local fused epilogue, ring4)
    k_gemm256<true,true,false><<<dim3(2*HIDD/256, NTOK/256), 512, 0, stream>>>(
        ub, WcatT, bcat, swb, NTOK, 2*HIDD, FFD, nullptr, nullptr);
    // ffmid = sw @ Wd + bd  (ring4)
    k_gemm256<true,false,false><<<dim3(FFD/256, NTOK/256), 512, 0, stream>>>(
        swb, WdT, bd, ub, NTOK, FFD, HIDD, nullptr, nullptr);
    // out = out1 + ffmid @ W2 + b2  (128^2, fp32 out + residual)
    k_gemm_bf16<true,true,false,false><<<dim3(CC/128, NTOK/128), 256, 0, stream>>>(
        ub, W2T, b2, out, out, NTOK, CC, FFD, nullptr);
}

// Round 17
// 349.084 us; speedup vs baseline: 1.1536x; 1.0615x over previous
//
#include <hip/hip_runtime.h>
#include <math.h>

#define BB   4
#define TT   1024
#define CC   768
#define HH   12
#define SS   64
#define FFD  3072
#define HIDD 2048
#define NTOK (BB*TT)          // 4096
#define EPSR 1e-6f

typedef __attribute__((ext_vector_type(8))) short bf16x8;
typedef __attribute__((ext_vector_type(4))) float f32x4;

__device__ __forceinline__ unsigned short f2bf(float f) {
    unsigned u = __float_as_uint(f);
    return (unsigned short)((u + 0x7FFFu + ((u >> 16) & 1u)) >> 16);
}
__device__ __forceinline__ float bfl(unsigned u) { return __uint_as_float(u << 16); }
__device__ __forceinline__ float bfh(unsigned u) { return __uint_as_float(u & 0xFFFF0000u); }
__device__ __forceinline__ unsigned pk2(float a, float b) {
    return (unsigned)f2bf(a) | ((unsigned)f2bf(b) << 16);
}

__device__ __forceinline__ void gload_lds16(const unsigned short* g, unsigned short* l) {
    __builtin_amdgcn_global_load_lds(
        (const __attribute__((address_space(1))) unsigned int*)g,
        (__attribute__((address_space(3))) unsigned int*)l, 16, 0, 0);
}

// ---------------- h_bf16 = bf16(x * rms_scale * gamma[c]) ------------------
__global__ void k_scale_gamma_b(const float* __restrict__ x, const float* __restrict__ g,
                                const float* __restrict__ part, unsigned short* __restrict__ h,
                                int n8, float invn, int npart) {
    __shared__ float sm[256];
    float s = 0.f;
    for (int i = threadIdx.x; i < npart; i += 256) s += part[i];
    sm[threadIdx.x] = s;
    __syncthreads();
    for (int off = 128; off > 0; off >>= 1) {
        if (threadIdx.x < off) sm[threadIdx.x] += sm[threadIdx.x + off];
        __syncthreads();
    }
    float sc = 1.0f / sqrtf(EPSR + sm[0] * invn);
    int i = blockIdx.x * blockDim.x + threadIdx.x;
    if (i >= n8) return;
    float4 v0 = ((const float4*)x)[2*i];
    float4 v1 = ((const float4*)x)[2*i+1];
    int c = (i * 8) % CC;
    float4 g0 = *(const float4*)(g + c);
    float4 g1v = *(const float4*)(g + c + 4);
    uint4 r;
    r.x = pk2(v0.x*sc*g0.x,  v0.y*sc*g0.y);
    r.y = pk2(v0.z*sc*g0.z,  v0.w*sc*g0.w);
    r.z = pk2(v1.x*sc*g1v.x, v1.y*sc*g1v.y);
    r.w = pk2(v1.z*sc*g1v.z, v1.w*sc*g1v.w);
    ((uint4*)h)[i] = r;
}

// ---------------- fused weight prep + rms1 sumsq ---------------------------
#define TQKV 1728
#define TWO  576
#define TW1  2304
#define TWW  6144
#define TWD  6144
#define TW2  2304
#define J0 (TQKV)
#define J1 (J0 + TWO)
#define J2 (J1 + TW1)
#define J3 (J2 + TWW)
#define J4 (J3 + TWW)
#define J5 (J4 + TWD)
#define J6 (J5 + TW2)
#define J7 (J6 + 16)
#define J8 (J7 + 128)
#define JSUM 1024
#define J9 (J8 + JSUM)

__device__ __forceinline__ void wT_tile(float (*tl)[33], const float* __restrict__ W,
                                        unsigned short* __restrict__ Wt,
                                        int K, int N, int t, int tx, int ty) {
    int nk = K >> 5;
    int k0 = (t % nk) * 32, n0 = (t / nk) * 32;
#pragma unroll
    for (int i = 0; i < 4; ++i)
        tl[ty + i*8][tx] = W[(size_t)(k0 + ty + i*8) * N + n0 + tx];
    __syncthreads();
#pragma unroll
    for (int i = 0; i < 4; ++i)
        Wt[(size_t)(n0 + ty + i*8) * K + k0 + tx] = f2bf(tl[tx][ty + i*8]);
}

// 16-block interleave: logical col j -> packed row (j&~15)*2 + ofs*16 + (j&15)
__device__ __forceinline__ void wT_tile_il(float (*tl)[33], const float* __restrict__ W,
                                           unsigned short* __restrict__ Wt,
                                           int K, int N, int t, int tx, int ty, int ofs) {
    int nk = K >> 5;
    int k0 = (t % nk) * 32, n0 = (t / nk) * 32;
#pragma unroll
    for (int i = 0; i < 4; ++i)
        tl[ty + i*8][tx] = W[(size_t)(k0 + ty + i*8) * N + n0 + tx];
    __syncthreads();
#pragma unroll
    for (int i = 0; i < 4; ++i) {
        int j = n0 + ty + i*8;
        int pr = ((j & ~15) << 1) + ofs*16 + (j & 15);
        Wt[(size_t)pr * K + k0 + tx] = f2bf(tl[tx][ty + i*8]);
    }
}

__global__ void k_prep(const float* __restrict__ Wq, const float* __restrict__ Wk,
                       const float* __restrict__ Wv, const float* __restrict__ Wo,
                       const float* __restrict__ W1, const float* __restrict__ Ww,
                       const float* __restrict__ Wg, const float* __restrict__ Wd,
                       const float* __restrict__ W2, const float* __restrict__ bw,
                       const float* __restrict__ bg, const float* __restrict__ x,
                       unsigned short* __restrict__ wqkvT, unsigned short* __restrict__ WoT,
                       unsigned short* __restrict__ W1T, unsigned short* __restrict__ WcatT,
                       unsigned short* __restrict__ WdT, unsigned short* __restrict__ W2T,
                       float* __restrict__ bcat, float* __restrict__ tab,
                       float* __restrict__ part) {
    __shared__ float tl[32][33];
    const int bid = blockIdx.x;
    const int tx = threadIdx.x & 31, ty = threadIdx.x >> 5;
    if (bid < J0) {
        int t = bid;
        int c0 = (t % 24) * 32;
        int s0 = ((t / 24) & 1) * 32;
        int z = t / 48, sel = z / HH, h = z % HH;
        const float* W = (sel == 0 ? Wq : (sel == 1 ? Wk : Wv)) + (size_t)h * CC * SS;
#pragma unroll
        for (int i = 0; i < 4; ++i)
            tl[ty + i*8][tx] = W[(size_t)(c0 + ty + i*8) * SS + s0 + tx];
        __syncthreads();
#pragma unroll
        for (int i = 0; i < 4; ++i) {
            int s = s0 + ty + i*8;
            int r;
            if (sel < 2) {                      // Q/K: rope-pair 16-block interleave
                int gp = h*32 + (s >> 1);       // global pair index
                r = (gp >> 4)*32 + ((s & 1) << 4) + (gp & 15);
            } else {
                r = h*SS + s;                   // V: plain layout
            }
            wqkvT[(size_t)(sel*CC + r) * CC + c0 + tx] = f2bf(tl[tx][ty + i*8]);
        }
    } else if (bid < J1) {
        wT_tile(tl, Wo, WoT, CC, CC, bid - J0, tx, ty);
    } else if (bid < J2) {
        wT_tile(tl, W1, W1T, CC, FFD, bid - J1, tx, ty);
    } else if (bid < J3) {
        wT_tile_il(tl, Ww, WcatT, FFD, HIDD, bid - J2, tx, ty, 0);
    } else if (bid < J4) {
        wT_tile_il(tl, Wg, WcatT, FFD, HIDD, bid - J3, tx, ty, 1);
    } else if (bid < J5) {
        wT_tile(tl, Wd, WdT, HIDD, FFD, bid - J4, tx, ty);
    } else if (bid < J6) {
        wT_tile(tl, W2, W2T, FFD, CC, bid - J5, tx, ty);
    } else if (bid < J7) {
        int ip = (bid - J6) * 256 + threadIdx.x;   // packed index in [0,4096)
        int lg = ((ip >> 5) << 4) + (ip & 15);     // logical col
        bcat[ip] = ((ip >> 4) & 1) ? bg[lg] : bw[lg];
    } else if (bid < J8) {
        int i = (bid - J7) * 256 + threadIdx.x;   // T*32
        int t = i >> 5, j = i & 31;
        float th = expf(-(float)j * 0.5756462732485115f);  // 10000^(-j/16)
        float ang = (float)t * th;
        tab[2*i]   = cosf(ang);
        tab[2*i+1] = sinf(ang);
    } else {
        float* sm = &tl[0][0];
        const int pb = bid - J8;
        const int n4 = NTOK * CC / 4;
        float s = 0.f;
        int stride = JSUM * 256;
        for (int i = pb * 256 + threadIdx.x; i < n4; i += stride) {
            float4 v = ((const float4*)x)[i];
            s += v.x*v.x + v.y*v.y + v.z*v.z + v.w*v.w;
        }
        sm[threadIdx.x] = s;
        __syncthreads();
        for (int off = 128; off > 0; off >>= 1) {
            if (threadIdx.x < off) sm[threadIdx.x] += sm[threadIdx.x + off];
            __syncthreads();
        }
        if (threadIdx.x == 0) part[pb] = sm[0];
    }
}

// ---------------- 128x128 bf16 MFMA GEMM — ring-4 counted-vmcnt (R9 port) --
// 4 waves (2x2), per-wave 64x64. LDS ring-4 x (A 8KB + B 8KB) = 64KB ->
// 2 blocks/CU. 4 loads/thread/slot; gate vmcnt(8) = slot t+1 landed.
// SSQ: also write per-block sum-of-squares of the fp32 output to part[].
#define G128STEP(t_, DOSTAGE, GATE)                                               \
    {                                                                             \
        const int st_ = (t_) & 3;                                                 \
        bf16x8 af[4], bf[4];                                                      \
        _Pragma("unroll")                                                         \
        for (int m = 0; m < 4; ++m) {                                             \
            int ra = wr * 64 + m * 16 + fr;                                       \
            af[m] = *(const bf16x8*)&As[st_][ra*32 + (fq ^ ((ra>>1)&3))*8];       \
            int rb = wc * 64 + m * 16 + fr;                                       \
            bf[m] = *(const bf16x8*)&Bs[st_][rb*32 + (fq ^ ((rb>>1)&3))*8];       \
        }                                                                         \
        if (DOSTAGE) stage((t_) + 3);                                             \
        __builtin_amdgcn_sched_barrier(0);                                        \
        __builtin_amdgcn_s_setprio(1);                                            \
        _Pragma("unroll")                                                         \
        for (int m = 0; m < 4; ++m)                                               \
            _Pragma("unroll")                                                     \
            for (int n = 0; n < 4; ++n)                                           \
                acc[m][n] = __builtin_amdgcn_mfma_f32_16x16x32_bf16(              \
                    af[m], bf[n], acc[m][n], 0, 0, 0);                            \
        __builtin_amdgcn_s_setprio(0);                                            \
        asm volatile("s_waitcnt " GATE ::: "memory");                             \
        __builtin_amdgcn_sched_barrier(0);                                        \
        __builtin_amdgcn_s_barrier();                                             \
    }

template<bool BIAS, bool RES, bool OUTB, bool SSQ>
__global__ __launch_bounds__(256) void k_gemm_bf16(
    const unsigned short* __restrict__ A, const unsigned short* __restrict__ Bt,
    const float* __restrict__ bias, const float* __restrict__ res,
    void* __restrict__ Cv, int M, int N, int K, float* __restrict__ ssq_part)
{
    __shared__ __align__(16) unsigned short As[4][128*32];
    __shared__ __align__(16) unsigned short Bs[4][128*32];
    __shared__ float smr[256];
    const int tid  = threadIdx.x;
    const int w    = tid >> 6, lane = tid & 63;
    const int wr   = w >> 1,  wc   = w & 1;
    const int row0 = blockIdx.y * 128, col0 = blockIdx.x * 128;

    f32x4 acc[4][4];
#pragma unroll
    for (int m = 0; m < 4; ++m)
#pragma unroll
        for (int n = 0; n < 4; ++n) acc[m][n] = (f32x4){0.f, 0.f, 0.f, 0.f};

    const int lr4 = lane >> 2;
    const int scb = lane & 3;

    auto stage = [&](int t) {
        const int st = t & 3;
#pragma unroll
        for (int i = 0; i < 2; ++i) {
            int lr = w * 32 + i * 16 + lr4;
            int cbs = scb ^ ((lr >> 1) & 3);
            const unsigned short* ga = A + (size_t)(row0 + lr) * K + t * 32 + cbs * 8;
            gload_lds16(ga, &As[st][(w * 32 + i * 16) * 32]);
            const unsigned short* gb = Bt + (size_t)(col0 + lr) * K + t * 32 + cbs * 8;
            gload_lds16(gb, &Bs[st][(w * 32 + i * 16) * 32]);
        }
    };

    const int nt = K / 32;    // >= 24 for all call sites
    const int fr = lane & 15, fq = lane >> 4;
    stage(0); stage(1); stage(2);
    asm volatile("s_waitcnt vmcnt(8)" ::: "memory");
    __builtin_amdgcn_s_barrier();
    int t = 0;
    for (; t < nt - 3; ++t) G128STEP(t, true, "vmcnt(8)");
    G128STEP(t, false, "vmcnt(4)"); ++t;
    G128STEP(t, false, "vmcnt(0)"); ++t;
    G128STEP(t, false, "vmcnt(0)");

    float ssq = 0.f;
#pragma unroll
    for (int m = 0; m < 4; ++m) {
#pragma unroll
        for (int n = 0; n < 4; ++n) {
            int col = col0 + wc * 64 + n * 16 + fr;
            float bv = BIAS ? bias[col] : 0.f;
#pragma unroll
            for (int j = 0; j < 4; ++j) {
                int row = row0 + wr * 64 + m * 16 + fq * 4 + j;
                size_t off = (size_t)row * N + col;
                float v = acc[m][n][j] + bv;
                if (RES) v += res[off];
                if (OUTB) ((unsigned short*)Cv)[off] = f2bf(v);
                else      ((float*)Cv)[off] = v;
                if (SSQ) ssq += v * v;
            }
        }
    }
    if (SSQ) {
        smr[tid] = ssq;
        __syncthreads();
        for (int off = 128; off > 0; off >>= 1) {
            if (tid < off) smr[tid] += smr[tid + off];
            __syncthreads();
        }
        if (tid == 0) ssq_part[blockIdx.y * gridDim.x + blockIdx.x] = smr[0];
    }
}

// ---------------- 256x256 bf16 MFMA GEMM — ring-4, 1-phase/K32 -------------
// Epilogue variants (all lane-local, block-uniform branches):
//  SWIGLU: 16-block interleaved wx/vx pairs -> swiglu, N/2 output.
//  QKV:    col0<1536 -> rope pairs (Q/K, pair-interleaved packing) written to
//          logical cols; col0>=1536 -> V stored transposed into vtg.
#define GSTEP(s_, DOSTAGE, GATE)                                                  \
    {                                                                             \
        const int st_ = (s_) & 3;                                                 \
        const unsigned short* pa_ = &ringA[st_][0];                               \
        const unsigned short* pb_ = &ringB[st_][0];                               \
        bf16x8 af[8], bv[4];                                                      \
        _Pragma("unroll")                                                         \
        for (int m = 0; m < 8; ++m)                                               \
            af[m] = *(const bf16x8*)&pa_[offA[m]];                                \
        _Pragma("unroll")                                                         \
        for (int n = 0; n < 4; ++n)                                               \
            bv[n] = *(const bf16x8*)&pb_[offB[n]];                                \
        if (DOSTAGE) { stageA((s_) + 3); stageB((s_) + 3); }                      \
        __builtin_amdgcn_sched_barrier(0);                                        \
        __builtin_amdgcn_s_setprio(1);                                            \
        _Pragma("unroll")                                                         \
        for (int m = 0; m < 8; ++m)                                               \
            _Pragma("unroll")                                                     \
            for (int n = 0; n < 4; ++n)                                           \
                acc[m][n] = __builtin_amdgcn_mfma_f32_16x16x32_bf16(              \
                    af[m], bv[n], acc[m][n], 0, 0, 0);                            \
        __builtin_amdgcn_s_setprio(0);                                            \
        asm volatile("s_waitcnt " GATE ::: "memory");                             \
        __builtin_amdgcn_sched_barrier(0);                                        \
        __builtin_amdgcn_s_barrier();                                             \
    }

template<bool BIAS, bool SWIGLU, bool QKV>
__global__ __launch_bounds__(512, 2) void k_gemm256(
    const unsigned short* __restrict__ A, const unsigned short* __restrict__ Bt,
    const float* __restrict__ bias, unsigned short* __restrict__ C,
    int M, int N, int K, const float* __restrict__ tab,
    unsigned short* __restrict__ vtg)
{
    __shared__ __align__(16) unsigned short ringA[4][256*32];
    __shared__ __align__(16) unsigned short ringB[4][256*32];
    const int tid = threadIdx.x;
    const int w = tid >> 6, lane = tid & 63;
    const int wm = w >> 2, wn = w & 3;
    const int fr = lane & 15, fq = lane >> 4;

    // XCD-bijective swizzle (all grids have nwg % 8 == 0)
    const int nwg = gridDim.x * gridDim.y;
    const int bid = blockIdx.y * gridDim.x + blockIdx.x;
    const int cpx = nwg >> 3;
    const int sbid = (bid & 7) * cpx + (bid >> 3);
    const int row0 = (sbid / gridDim.x) * 256;
    const int col0 = (sbid % gridDim.x) * 256;

    f32x4 acc[8][4];
#pragma unroll
    for (int m = 0; m < 8; ++m)
#pragma unroll
        for (int n = 0; n < 4; ++n) acc[m][n] = (f32x4){0.f, 0.f, 0.f, 0.f};

    // hoisted stage source pointers (only kb = t*32 varies)
    const int c0 = tid, c1 = 512 + tid;
    const int r0 = c0 >> 2, p0 = ((c0 & 3) ^ ((r0 >> 1) & 3)) * 8;
    const int r1 = c1 >> 2, p1 = ((c1 & 3) ^ ((r1 >> 1) & 3)) * 8;
    const unsigned short* aS0 = A  + (size_t)(row0 + r0) * K + p0;
    const unsigned short* aS1 = A  + (size_t)(row0 + r1) * K + p1;
    const unsigned short* bS0 = Bt + (size_t)(col0 + r0) * K + p0;
    const unsigned short* bS1 = Bt + (size_t)(col0 + r1) * K + p1;
    const int dL = w * 512;            // LDS dst offset (elements), q=0
    auto stageA = [&](int t) {
        const int st = t & 3;
        const int kb = t * 32;
        gload_lds16(aS0 + kb, &ringA[st][dL]);
        gload_lds16(aS1 + kb, &ringA[st][4096 + dL]);
    };
    auto stageB = [&](int t) {
        const int st = t & 3;
        const int kb = t * 32;
        gload_lds16(bS0 + kb, &ringB[st][dL]);
        gload_lds16(bS1 + kb, &ringB[st][4096 + dL]);
    };

    // hoisted frag read offsets
    int offA[8], offB[4];
#pragma unroll
    for (int m = 0; m < 8; ++m) {
        int ra = wm*128 + m*16 + fr;
        offA[m] = ra*32 + (fq ^ ((ra >> 1) & 3))*8;
    }
#pragma unroll
    for (int n = 0; n < 4; ++n) {
        int rb = wn*64 + n*16 + fr;
        offB[n] = rb*32 + (fq ^ ((rb >> 1) & 3))*8;
    }

    const int S = K >> 5;     // k32 steps
    stageA(0); stageB(0); stageA(1); stageB(1); stageA(2); stageB(2);
    asm volatile("s_waitcnt vmcnt(8)" ::: "memory");
    __builtin_amdgcn_s_barrier();
    int s = 0;
    for (; s < S - 3; ++s) GSTEP(s, true, "vmcnt(8)");
    GSTEP(s, false, "vmcnt(4)"); ++s;
    GSTEP(s, false, "vmcnt(0)"); ++s;
    GSTEP(s, false, "vmcnt(0)");

    // epilogue: row = wm*128 + m*16 + fq*4 + j, col = wn*64 + n*16 + fr
    if (QKV) {
        if (col0 < 1536) {
            // Q or K section: rope pairs (packed even col = acc[m][2np],
            // odd partner = acc[m][2np+1]); write to LOGICAL columns.
            const int sel = (col0 >= CC) ? 1 : 0;
#pragma unroll
            for (int m = 0; m < 8; ++m) {
#pragma unroll
                for (int np = 0; np < 2; ++np) {
                    int colw = col0 + wn*64 + np*32 + fr;     // even-parity packed col
                    int ps = colw - sel*CC;
                    int gp = (ps >> 5)*16 + (ps & 15);        // h*32 + j
                    int hh = gp >> 5, jj = gp & 31;
                    int ce = sel*CC + hh*64 + 2*jj;           // logical even col
#pragma unroll
                    for (int j = 0; j < 4; ++j) {
                        int row = row0 + wm*128 + m*16 + fq*4 + j;
                        int t = row & (TT - 1);
                        float cs = tab[(t*32 + jj)*2];
                        float sn = tab[(t*32 + jj)*2 + 1];
                        float e = acc[m][2*np][j];
                        float o = acc[m][2*np+1][j];
                        *(unsigned*)(C + (size_t)row * N + ce) =
                            pk2(e*cs - o*sn, o*cs + e*sn);
                    }
                }
            }
        } else {
            // V section: store transposed into vtg[bh][64][T]
            const int vb = row0 >> 10;                        // batch (block-uniform)
            const int tb = (row0 & (TT-1)) + wm*128;
#pragma unroll
            for (int m = 0; m < 8; ++m) {
#pragma unroll
                for (int n = 0; n < 4; ++n) {
                    int col = col0 + wn*64 + n*16 + fr;
                    int d = col - 1536;                       // h*64 + dd
                    int t0 = tb + m*16 + fq*4;
                    unsigned short* dst = vtg +
                        ((size_t)(vb*HH + (d >> 6))*64 + (d & 63))*TT + t0;
                    uint2 val;
                    val.x = pk2(acc[m][n][0], acc[m][n][1]);
                    val.y = pk2(acc[m][n][2], acc[m][n][3]);
                    *(uint2*)dst = val;
                }
            }
        }
    } else if (SWIGLU) {
#pragma unroll
        for (int m = 0; m < 8; ++m) {
#pragma unroll
            for (int n = 0; n < 4; n += 2) {
                int colw = col0 + wn*64 + n*16 + fr;       // packed wx col
                float bw_ = BIAS ? bias[colw] : 0.f;
                float bg_ = BIAS ? bias[colw + 16] : 0.f;
                int colo = ((colw >> 5) << 4) + (colw & 15); // logical out col
#pragma unroll
                for (int j = 0; j < 4; ++j) {
                    int row = row0 + wm*128 + m*16 + fq*4 + j;
                    float wx = acc[m][n][j] + bw_;
                    float vx = acc[m][n+1][j] + bg_;
                    float sw = wx * vx / (1.f + __expf(-vx));
                    C[(size_t)row * (N >> 1) + colo] = f2bf(sw);
                }
            }
        }
    } else {
#pragma unroll
        for (int m = 0; m < 8; ++m) {
#pragma unroll
            for (int n = 0; n < 4; ++n) {
                int col = col0 + wn*64 + n*16 + fr;
                float bvb = BIAS ? bias[col] : 0.f;
#pragma unroll
                for (int j = 0; j < 4; ++j) {
                    int row = row0 + wm*128 + m*16 + fq*4 + j;
                    C[(size_t)row * N + col] = f2bf(acc[m][n][j] + bvb);
                }
            }
        }
    }
}

// ---------------- MFMA flash attention (causal), bf16 --------------------
__global__ __launch_bounds__(256) void k_attn_mfma(
    const unsigned short* __restrict__ qkv, const unsigned short* __restrict__ vtg,
    unsigned short* __restrict__ attn)
{
    __shared__ __align__(16) unsigned short Ks[2][64*64];
    __shared__ __align__(16) unsigned short Vs[2][64*64];
    __shared__ __align__(16) unsigned short Ps[4][16*72];
    const int tid = threadIdx.x;
    const int w = tid >> 6, lane = tid & 63;
    const int fr = lane & 15, fq = lane >> 4;
    const int bh = blockIdx.x, b = bh / HH, h = bh % HH;
    const int qb = blockIdx.y * 64;
    const int nkt = qb / 64 + 1;
    const float scale = 0.03608439182435161f;  // 768^-0.5

    bf16x8 qf[2];
    {
        const unsigned short* qp = qkv + (size_t)(b*TT + qb + w*16 + fr)*(3*CC) + h*SS + fq*8;
        qf[0] = *(const bf16x8*)qp;
        qf[1] = *(const bf16x8*)(qp + 32);
    }

    auto stage = [&](int kt, int buf) {
        const unsigned short* kbase = qkv + (size_t)(b*TT + kt*64)*(3*CC) + CC + h*SS;
        const unsigned short* vbase = vtg + ((size_t)bh*64)*TT + kt*64;
#pragma unroll
        for (int p = 0; p < 2; ++p) {
            int s = p*256 + tid;
            int row = s >> 3;
            int blk = (s & 7) ^ (row & 7);
            gload_lds16(kbase + (size_t)row*(3*CC) + blk*8, &Ks[buf][(p*256 + w*64)*8]);
            gload_lds16(vbase + (size_t)row*TT + blk*8,     &Vs[buf][(p*256 + w*64)*8]);
        }
    };

    float m[4] = {-INFINITY, -INFINITY, -INFINITY, -INFINITY};
    float l[4] = {0.f, 0.f, 0.f, 0.f};
    f32x4 oacc[4];
#pragma unroll
    for (int n = 0; n < 4; ++n) oacc[n] = (f32x4){0.f, 0.f, 0.f, 0.f};

    stage(0, 0);
    int cur = 0;
    for (int kt = 0; kt < nkt; ++kt) {
        __syncthreads();
        if (kt + 1 < nkt) stage(kt + 1, cur ^ 1);

        f32x4 sacc[4];
#pragma unroll
        for (int n = 0; n < 4; ++n) sacc[n] = (f32x4){0.f, 0.f, 0.f, 0.f};
#pragma unroll
        for (int ks = 0; ks < 2; ++ks) {
#pragma unroll
            for (int n = 0; n < 4; ++n) {
                int row = n*16 + fr;
                bf16x8 kf = *(const bf16x8*)&Ks[cur][row*64 + ((ks*4 + fq) ^ (row & 7))*8];
                sacc[n] = __builtin_amdgcn_mfma_f32_16x16x32_bf16(qf[ks], kf, sacc[n], 0, 0, 0);
            }
        }

        float sv[4][4];
        const bool lastt = (kt == nkt - 1);
        const int qloc = w*16 + fq*4;
#pragma unroll
        for (int n = 0; n < 4; ++n) {
            int kloc = n*16 + fr;
#pragma unroll
            for (int j = 0; j < 4; ++j) {
                float vv = sacc[n][j] * scale;
                if (lastt && kloc > qloc + j) vv = -INFINITY;
                sv[j][n] = vv;
            }
        }
        float mx[4], ls[4];
#pragma unroll
        for (int j = 0; j < 4; ++j)
            mx[j] = fmaxf(fmaxf(sv[j][0], sv[j][1]), fmaxf(sv[j][2], sv[j][3]));
#pragma unroll
        for (int d = 1; d < 16; d <<= 1)
#pragma unroll
            for (int j = 0; j < 4; ++j) mx[j] = fmaxf(mx[j], __shfl_xor(mx[j], d));
        float corr[4];
#pragma unroll
        for (int j = 0; j < 4; ++j) {
            float nm = fmaxf(m[j], mx[j]);
            corr[j] = __expf(m[j] - nm);
            m[j] = nm;
        }
#pragma unroll
        for (int j = 0; j < 4; ++j) {
            float s0 = 0.f;
#pragma unroll
            for (int n = 0; n < 4; ++n) {
                float p = __expf(sv[j][n] - m[j]);
                sv[j][n] = p;
                s0 += p;
            }
            ls[j] = s0;
        }
#pragma unroll
        for (int d = 1; d < 16; d <<= 1)
#pragma unroll
            for (int j = 0; j < 4; ++j) ls[j] += __shfl_xor(ls[j], d);
#pragma unroll
        for (int j = 0; j < 4; ++j) l[j] = l[j]*corr[j] + ls[j];
#pragma unroll
        for (int n = 0; n < 4; ++n)
#pragma unroll
            for (int j = 0; j < 4; ++j) oacc[n][j] *= corr[j];

#pragma unroll
        for (int j = 0; j < 4; ++j)
#pragma unroll
            for (int n = 0; n < 4; ++n)
                Ps[w][(fq*4 + j)*72 + n*16 + fr] = f2bf(sv[j][n]);

#pragma unroll
        for (int ks = 0; ks < 2; ++ks) {
            bf16x8 pf = *(const bf16x8*)&Ps[w][fr*72 + ks*32 + fq*8];
#pragma unroll
            for (int n = 0; n < 4; ++n) {
                int row = n*16 + fr;
                bf16x8 vf = *(const bf16x8*)&Vs[cur][row*64 + ((ks*4 + fq) ^ (row & 7))*8];
                oacc[n] = __builtin_amdgcn_mfma_f32_16x16x32_bf16(pf, vf, oacc[n], 0, 0, 0);
            }
        }
        cur ^= 1;
    }

    float inv[4];
#pragma unroll
    for (int j = 0; j < 4; ++j) inv[j] = 1.0f / l[j];
#pragma unroll
    for (int n = 0; n < 4; ++n)
#pragma unroll
        for (int j = 0; j < 4; ++j) {
            size_t off = (size_t)(b*TT + qb + w*16 + fq*4 + j)*CC + h*SS + n*16 + fr;
            attn[off] = f2bf(oacc[n][j] * inv[j]);
        }
}

// ---------------- launch ---------------------------------------------------
extern "C" void kernel_launch(void* const* d_in, const int* in_sizes, int n_in,
                              void* d_out, int out_size, void* d_ws, size_t ws_size,
                              hipStream_t stream)
{
    const float* x  = (const float*)d_in[0];
    const float* Wq = (const float*)d_in[1];
    const float* Wk = (const float*)d_in[2];
    const float* Wv = (const float*)d_in[3];
    const float* Wo = (const float*)d_in[4];
    const float* g1 = (const float*)d_in[5];
    const float* g2 = (const float*)d_in[6];
    const float* W1 = (const float*)d_in[7];
    const float* b1 = (const float*)d_in[8];
    const float* Ww = (const float*)d_in[9];
    const float* bw = (const float*)d_in[10];
    const float* Wg = (const float*)d_in[11];
    const float* bg = (const float*)d_in[12];
    const float* Wd = (const float*)d_in[13];
    const float* bd = (const float*)d_in[14];
    const float* W2 = (const float*)d_in[15];
    const float* b2 = (const float*)d_in[16];
    float* out = (float*)d_out;

    char* p = (char*)d_ws;
    auto alloc = [&](size_t bytes) { char* r = p; p += (bytes + 255) & ~(size_t)255; return r; };

    float*          part   = (float*)alloc(4096);
    float*          tab    = (float*)alloc((size_t)TT*32*2*4);
    float*          bcat   = (float*)alloc((size_t)2*HIDD*4);
    unsigned short* hb     = (unsigned short*)alloc((size_t)NTOK*CC*2);
    unsigned short* wqkvT  = (unsigned short*)alloc((size_t)3*CC*CC*2);
    unsigned short* qkvb   = (unsigned short*)alloc((size_t)NTOK*3*CC*2);
    unsigned short* vtg    = (unsigned short*)alloc((size_t)BB*HH*SS*TT*2);
    unsigned short* attnb  = (unsigned short*)alloc((size_t)NTOK*CC*2);
    unsigned short* WoT    = (unsigned short*)alloc((size_t)CC*CC*2);
    unsigned short* W1T    = (unsigned short*)alloc((size_t)FFD*CC*2);
    unsigned short* ub     = (unsigned short*)alloc((size_t)NTOK*FFD*2);
    unsigned short* WcatT  = (unsigned short*)alloc((size_t)2*HIDD*FFD*2);
    unsigned short* swb    = (unsigned short*)alloc((size_t)NTOK*HIDD*2);
    unsigned short* WdT    = (unsigned short*)alloc((size_t)FFD*HIDD*2);
    unsigned short* W2T    = (unsigned short*)alloc((size_t)CC*FFD*2);

    const int n = NTOK * CC;

    // fused weight prep + rms1 sumsq
    k_prep<<<J9, 256, 0, stream>>>(Wq, Wk, Wv, Wo, W1, Ww, Wg, Wd, W2, bw, bg, x,
                                   wqkvT, WoT, W1T, WcatT, WdT, W2T, bcat, tab, part);

    // rms1 -> h (bf16)
    k_scale_gamma_b<<<(n/8)/256, 256, 0, stream>>>(x, g1, part, hb, n/8,
                                                   1.0f/(float)n, JSUM);

    // qkv = h @ WqkvT^T with fused rope(Q,K) + V-transpose epilogue
    k_gemm256<false,false,true><<<dim3(3*CC/256, NTOK/256), 512, 0, stream>>>(
        hb, wqkvT, nullptr, qkvb, NTOK, 3*CC, CC, tab, vtg);

    // attention (MFMA)
    k_attn_mfma<<<dim3(BB*HH, TT/64), 256, 0, stream>>>(qkvb, vtg, attnb);

    // out1 = attn @ Wo + x  (128^2 ring4, fp32 out) + fused rms2 sumsq partials
    k_gemm_bf16<false,true,false,true><<<dim3(CC/128, NTOK/128), 256, 0, stream>>>(
        attnb, WoT, nullptr, x, out, NTOK, CC, CC, part);

    // rms2 -> h2 (reduces 192 partials from Wo epilogue)
    k_scale_gamma_b<<<(n/8)/256, 256, 0, stream>>>(out, g2, part, hb, n/8,
                                                   1.0f/(float)n, (CC/128)*(NTOK/128));

    // u = h2 @ W1 + b1  (ring4)
    k_gemm256<true,false,false><<<dim3(FFD/256, NTOK/256), 512, 0, stream>>>(
        hb, W1T, b1, ub, NTOK, FFD, CC, nullptr, nullptr);
    // swb = swiglu(u @ WcatT + bcat)  (lane-local fused epilogue, ring4)
    k_gemm256<true,true,false><<<dim3(2*HIDD/256, NTOK/256), 512, 0, stream>>>(
        ub, WcatT, bcat, swb, NTOK, 2*HIDD, FFD, nullptr, nullptr);
    // ffmid = sw @ Wd + bd  (ring4)
    k_gemm256<true,false,false><<<dim3(FFD/256, NTOK/256), 512, 0, stream>>>(
        swb, WdT, bd, ub, NTOK, FFD, HIDD, nullptr, nullptr);
    // out = out1 + ffmid @ W2 + b2  (128^2 ring4, fp32 out + residual)
    k_gemm_bf16<true,true,false,false><<<dim3(CC/128, NTOK/128), 256, 0, stream>>>(
        ub, W2T, b2, out, out, NTOK, CC, FFD, nullptr);
}